// Round 3
// baseline (4424.643 us; speedup 1.0000x reference)
//
#include <hip/hip_runtime.h>
#include <hip/hip_bf16.h>
#include <hip/hip_fp16.h>
#include <type_traits>

// Problem constants (fixed by the reference)
#define BATCH  2
#define SEQ    2048
#define DMODEL 1024
#define NHEAD  16
#define DHEAD  64

__device__ __forceinline__ float to_float(float x) { return x; }
__device__ __forceinline__ float to_float(__hip_bfloat16 x) { return __bfloat162float(x); }
__device__ __forceinline__ float to_float(__half x) { return __half2float(x); }
__device__ __forceinline__ void store_val(float* p, float v) { *p = v; }
__device__ __forceinline__ void store_val(__hip_bfloat16* p, float v) { *p = __float2bfloat16(v); }
__device__ __forceinline__ void store_val(__half* p, float v) { *p = __float2half(v); }

// ---------------------------------------------------------------------------
// Tiled GEMM: C[M,N] = A[M,K] @ B[K,N], fp32 accumulate.
// BM=BN=64, BK=16, 256 threads, 4x4 microtile per thread.
// M,N,K multiples of 64/64/16 (4096/1024/1024) -> no bounds checks.
// ---------------------------------------------------------------------------
template <typename AT, typename BT, typename CT>
__global__ __launch_bounds__(256) void gemm_tiled(const AT* __restrict__ A,
                                                  const BT* __restrict__ Bm,
                                                  CT* __restrict__ C,
                                                  int M, int N, int K)
{
    __shared__ float As[16][65];  // [k][m], padded
    __shared__ float Bs[16][68];  // [k][n], padded

    const int t  = threadIdx.x;
    const int m0 = blockIdx.y * 64;
    const int n0 = blockIdx.x * 64;

    const int arow = t >> 2;          // 0..63
    const int acol = (t & 3) << 2;    // 0,4,8,12
    const int brow = t >> 4;          // 0..15
    const int bcol = (t & 15) << 2;   // 0..60
    const int ty   = t >> 4;          // 0..15
    const int tx   = t & 15;          // 0..15

    float acc[4][4] = {};

    for (int k0 = 0; k0 < K; k0 += 16) {
#pragma unroll
        for (int i = 0; i < 4; i++)
            As[acol + i][arow] = to_float(A[(size_t)(m0 + arow) * K + (k0 + acol + i)]);
#pragma unroll
        for (int i = 0; i < 4; i++)
            Bs[brow][bcol + i] = to_float(Bm[(size_t)(k0 + brow) * N + (n0 + bcol + i)]);
        __syncthreads();

#pragma unroll
        for (int kk = 0; kk < 16; kk++) {
            float a[4], b[4];
#pragma unroll
            for (int i = 0; i < 4; i++) a[i] = As[kk][ty * 4 + i];
#pragma unroll
            for (int j = 0; j < 4; j++) b[j] = Bs[kk][tx * 4 + j];
#pragma unroll
            for (int i = 0; i < 4; i++)
#pragma unroll
                for (int j = 0; j < 4; j++)
                    acc[i][j] += a[i] * b[j];
        }
        __syncthreads();
    }

#pragma unroll
    for (int i = 0; i < 4; i++)
#pragma unroll
        for (int j = 0; j < 4; j++)
            store_val(&C[(size_t)(m0 + ty * 4 + i) * N + (n0 + tx * 4 + j)], acc[i][j]);
}

// ---------------------------------------------------------------------------
// Causal attention, one wave (64 threads) per (b, h, query-row).
// Reference quirk: softmax FIRST on UNSCALED scores, then divide by sqrt(64)=8.
// Causal: keys kk <= qi (triu k=1 masked, diagonal allowed).
// Layouts: [b][seq][h*64+d].
// qa serves as INPUT qh and OUTPUT att: address (b,q,h*64+d) is read only by
// block (b,h,q) and written only by that same block after its read -> safe.
// ---------------------------------------------------------------------------
template <typename QT, typename KT, typename VT>
__global__ __launch_bounds__(64) void attn_kernel(QT* qa,
                                                  const KT* __restrict__ kh,
                                                  const VT* __restrict__ vh)
{
    __shared__ float s[SEQ];                   // score row (8 KB)
    __shared__ __align__(16) float qs[DHEAD];  // this row's q vector

    const int bid  = blockIdx.x;
    const int qi   = bid & (SEQ - 1);          // SEQ = 2^11
    const int h    = (bid >> 11) & (NHEAD - 1);
    const int b    = bid >> 15;
    const int lane = threadIdx.x;

    const size_t rowbase = ((size_t)b * SEQ + qi) * DMODEL + h * DHEAD;
    const KT* kbase = kh + (size_t)b * SEQ * DMODEL + h * DHEAD;
    const VT* vbase = vh + (size_t)b * SEQ * DMODEL + h * DHEAD;

    qs[lane] = to_float(qa[rowbase + lane]);
    __syncthreads();

    const int nk = qi + 1;

    // Phase 1: scores (each lane owns keys lane, lane+64, ...)
    float lmax = -1e30f;
    for (int kk = lane; kk < nk; kk += 64) {
        float dot = 0.f;
        if constexpr (std::is_same_v<KT, float>) {
            const float4* k4 = (const float4*)(kbase + (size_t)kk * DMODEL);
            const float4* q4 = (const float4*)qs;
#pragma unroll
            for (int d = 0; d < DHEAD / 4; d++) {
                float4 a = q4[d], bb = k4[d];
                dot += a.x * bb.x + a.y * bb.y + a.z * bb.z + a.w * bb.w;
            }
        } else {
            const KT* krow = kbase + (size_t)kk * DMODEL;
#pragma unroll
            for (int d = 0; d < DHEAD; d++) dot += qs[d] * to_float(krow[d]);
        }
        s[kk] = dot;
        lmax  = fmaxf(lmax, dot);
    }
#pragma unroll
    for (int off = 32; off > 0; off >>= 1) lmax = fmaxf(lmax, __shfl_xor(lmax, off, 64));
    __syncthreads();

    // Phase 2: exp + sum (softmax on UNSCALED scores)
    float lsum = 0.f;
    for (int kk = lane; kk < nk; kk += 64) {
        float e = __expf(s[kk] - lmax);
        s[kk]   = e;
        lsum += e;
    }
#pragma unroll
    for (int off = 32; off > 0; off >>= 1) lsum += __shfl_xor(lsum, off, 64);
    const float scale = 1.0f / (lsum * 8.0f);  // includes the post-softmax /sqrt(64)
    __syncthreads();

    // Phase 3: out[d=lane] = scale * sum_k w_k * v[k][lane]   (coalesced V loads)
    float acc = 0.f;
    int kk = 0;
    for (; kk + 4 <= nk; kk += 4) {
        acc += s[kk + 0] * to_float(vbase[(size_t)(kk + 0) * DMODEL + lane]);
        acc += s[kk + 1] * to_float(vbase[(size_t)(kk + 1) * DMODEL + lane]);
        acc += s[kk + 2] * to_float(vbase[(size_t)(kk + 2) * DMODEL + lane]);
        acc += s[kk + 3] * to_float(vbase[(size_t)(kk + 3) * DMODEL + lane]);
    }
    for (; kk < nk; kk++)
        acc += s[kk] * to_float(vbase[(size_t)kk * DMODEL + lane]);

    store_val(&qa[rowbase + lane], acc * scale);   // write att in place of qh
}

// ---------------------------------------------------------------------------
// Launch. Inputs (setup_inputs order): q, k, v, mask(ignored), Wq, Wk, Wv, Wo.
// All float32. Workspace tiers (critical q/k score path stays fp32 down to
// ws_size = 32 MB):
//   T1 ws>=48MB: qh,kh,vh fp32 in ws; att aliases qh.
//   T2 ws>=40MB: qh,kh fp32 in ws; vh bf16 in ws; att aliases qh.
//   T2' ws>=32MB: qh,kh fp32 in ws; vh bf16 stored in d_out (read fully
//                 before the final GEMM overwrites d_out); att aliases qh.
//   T3 else:     qh,kh fp16 in ws; vh bf16 in d_out (last resort).
// ---------------------------------------------------------------------------
extern "C" void kernel_launch(void* const* d_in, const int* in_sizes, int n_in,
                              void* d_out, int out_size, void* d_ws, size_t ws_size,
                              hipStream_t stream)
{
    const float* q  = (const float*)d_in[0];
    const float* k  = (const float*)d_in[1];
    const float* v  = (const float*)d_in[2];
    const float* Wq = (const float*)d_in[4];
    const float* Wk = (const float*)d_in[5];
    const float* Wv = (const float*)d_in[6];
    const float* Wo = (const float*)d_in[7];
    float* out = (float*)d_out;

    const int    M   = BATCH * SEQ;            // 4096
    const size_t npe = (size_t)M * DMODEL;     // 4,194,304 elements per tensor

    dim3 gthreads(256);
    dim3 ggrid(DMODEL / 64, M / 64);           // (16, 64)
    dim3 agrid(BATCH * NHEAD * SEQ);           // 65536 blocks of 64

    if (ws_size >= 3 * npe * sizeof(float)) {                      // 48 MB
        float* qh = (float*)d_ws;
        float* kh = qh + npe;
        float* vh = kh + npe;
        gemm_tiled<float, float, float><<<ggrid, gthreads, 0, stream>>>(q, Wq, qh, M, DMODEL, DMODEL);
        gemm_tiled<float, float, float><<<ggrid, gthreads, 0, stream>>>(k, Wk, kh, M, DMODEL, DMODEL);
        gemm_tiled<float, float, float><<<ggrid, gthreads, 0, stream>>>(v, Wv, vh, M, DMODEL, DMODEL);
        attn_kernel<float, float, float><<<agrid, dim3(64), 0, stream>>>(qh, kh, vh);
        gemm_tiled<float, float, float><<<ggrid, gthreads, 0, stream>>>(qh, Wo, out, M, DMODEL, DMODEL);
    } else if (ws_size >= 2 * npe * sizeof(float) + npe * sizeof(__hip_bfloat16)) {  // 40 MB
        float* qh = (float*)d_ws;
        float* kh = qh + npe;
        __hip_bfloat16* vh = (__hip_bfloat16*)(kh + npe);
        gemm_tiled<float, float, float><<<ggrid, gthreads, 0, stream>>>(q, Wq, qh, M, DMODEL, DMODEL);
        gemm_tiled<float, float, float><<<ggrid, gthreads, 0, stream>>>(k, Wk, kh, M, DMODEL, DMODEL);
        gemm_tiled<float, float, __hip_bfloat16><<<ggrid, gthreads, 0, stream>>>(v, Wv, vh, M, DMODEL, DMODEL);
        attn_kernel<float, float, __hip_bfloat16><<<agrid, dim3(64), 0, stream>>>(qh, kh, vh);
        gemm_tiled<float, float, float><<<ggrid, gthreads, 0, stream>>>(qh, Wo, out, M, DMODEL, DMODEL);
    } else if (ws_size >= 2 * npe * sizeof(float)) {               // 32 MB
        float* qh = (float*)d_ws;
        float* kh = qh + npe;
        __hip_bfloat16* vh = (__hip_bfloat16*)d_out;   // lives in d_out until final GEMM
        gemm_tiled<float, float, float><<<ggrid, gthreads, 0, stream>>>(q, Wq, qh, M, DMODEL, DMODEL);
        gemm_tiled<float, float, float><<<ggrid, gthreads, 0, stream>>>(k, Wk, kh, M, DMODEL, DMODEL);
        gemm_tiled<float, float, __hip_bfloat16><<<ggrid, gthreads, 0, stream>>>(v, Wv, vh, M, DMODEL, DMODEL);
        attn_kernel<float, float, __hip_bfloat16><<<agrid, dim3(64), 0, stream>>>(qh, kh, vh);
        gemm_tiled<float, float, float><<<ggrid, gthreads, 0, stream>>>(qh, Wo, out, M, DMODEL, DMODEL);
    } else {                                                       // last resort (16 MB)
        __half* qh = (__half*)d_ws;
        __half* kh = qh + npe;
        __hip_bfloat16* vh = (__hip_bfloat16*)d_out;
        gemm_tiled<float, float, __half><<<ggrid, gthreads, 0, stream>>>(q, Wq, qh, M, DMODEL, DMODEL);
        gemm_tiled<float, float, __half><<<ggrid, gthreads, 0, stream>>>(k, Wk, kh, M, DMODEL, DMODEL);
        gemm_tiled<float, float, __hip_bfloat16><<<ggrid, gthreads, 0, stream>>>(v, Wv, vh, M, DMODEL, DMODEL);
        attn_kernel<__half, __half, __hip_bfloat16><<<agrid, dim3(64), 0, stream>>>(qh, kh, vh);
        gemm_tiled<__half, float, float><<<ggrid, gthreads, 0, stream>>>(qh, Wo, out, M, DMODEL, DMODEL);
    }
}

// Round 4
// 767.562 us; speedup vs baseline: 5.7645x; 5.7645x over previous
//
#include <hip/hip_runtime.h>
#include <hip/hip_bf16.h>

// Problem constants (fixed by the reference)
#define BATCH  2
#define SEQ    2048
#define DMODEL 1024
#define NHEAD  16
#define DHEAD  64

typedef _Float16 f16x8 __attribute__((ext_vector_type(8)));
typedef float    f32x4 __attribute__((ext_vector_type(4)));

__device__ __forceinline__ float to_float(float x) { return x; }
__device__ __forceinline__ float to_float(__hip_bfloat16 x) { return __bfloat162float(x); }
__device__ __forceinline__ void store_val(float* p, float v) { *p = v; }
__device__ __forceinline__ void store_val(__hip_bfloat16* p, float v) { *p = __float2bfloat16(v); }

// ---------------------------------------------------------------------------
// Tiled GEMM (unchanged from passing round): C[M,N] = A[M,K] @ B[K,N], fp32.
// ---------------------------------------------------------------------------
template <typename AT, typename BT, typename CT>
__global__ __launch_bounds__(256) void gemm_tiled(const AT* __restrict__ A,
                                                  const BT* __restrict__ Bm,
                                                  CT* __restrict__ C,
                                                  int M, int N, int K)
{
    __shared__ float As[16][65];
    __shared__ float Bs[16][68];

    const int t  = threadIdx.x;
    const int m0 = blockIdx.y * 64;
    const int n0 = blockIdx.x * 64;

    const int arow = t >> 2;
    const int acol = (t & 3) << 2;
    const int brow = t >> 4;
    const int bcol = (t & 15) << 2;
    const int ty   = t >> 4;
    const int tx   = t & 15;

    float acc[4][4] = {};

    for (int k0 = 0; k0 < K; k0 += 16) {
#pragma unroll
        for (int i = 0; i < 4; i++)
            As[acol + i][arow] = to_float(A[(size_t)(m0 + arow) * K + (k0 + acol + i)]);
#pragma unroll
        for (int i = 0; i < 4; i++)
            Bs[brow][bcol + i] = to_float(Bm[(size_t)(k0 + brow) * N + (n0 + bcol + i)]);
        __syncthreads();

#pragma unroll
        for (int kk = 0; kk < 16; kk++) {
            float a[4], b[4];
#pragma unroll
            for (int i = 0; i < 4; i++) a[i] = As[kk][ty * 4 + i];
#pragma unroll
            for (int j = 0; j < 4; j++) b[j] = Bs[kk][tx * 4 + j];
#pragma unroll
            for (int i = 0; i < 4; i++)
#pragma unroll
                for (int j = 0; j < 4; j++)
                    acc[i][j] += a[i] * b[j];
        }
        __syncthreads();
    }

#pragma unroll
    for (int i = 0; i < 4; i++)
#pragma unroll
        for (int j = 0; j < 4; j++)
            store_val(&C[(size_t)(m0 + ty * 4 + i) * N + (n0 + tx * 4 + j)], acc[i][j]);
}

// ---------------------------------------------------------------------------
// MFMA flash attention (causal). Block = 64 queries x one (b,h); 4 waves x 16 q.
// Softmax on UNSCALED scores (reference quirk), /sqrt(64)=8 applied at the end.
// Scores: split-f16 (hi+lo) QK^T, 3 MFMAs, fp32 accumulate -> fp32-level accuracy.
// PV: P in f16 (values <= 1), V in f16 (from bf16), fp32 accumulate.
// MFMA 16x16x32_f16 layouts (verified in guide):
//   A: lane(m=lane&15, quad=lane>>4) holds A[m][quad*8+j], j=0..7
//   B: lane(n=lane&15, quad)         holds B[quad*8+j][n]
//   C/D: col=lane&15, row=quad*4+reg
// ---------------------------------------------------------------------------
#define LDS_STRIDE 72                       // halves per row (64+8 pad) = 144 B
#define KHI_OFF 0
#define KLO_OFF (64 * LDS_STRIDE)
#define VT_OFF  (2 * 64 * LDS_STRIDE)
#define P_OFF   (3 * 64 * LDS_STRIDE)
#define P_WAVE  (16 * LDS_STRIDE)
#define SMEM_HALVES (3 * 64 * LDS_STRIDE + 4 * 16 * LDS_STRIDE)  // 18432 = 36 KB

__global__ __launch_bounds__(256) void attn_mfma(float* __restrict__ qa,   // qh in, att out (aliased)
                                                 const float* __restrict__ kh,
                                                 const __hip_bfloat16* __restrict__ vh)
{
    __shared__ __align__(16) _Float16 smem[SMEM_HALVES];

    const int qt = (SEQ / 64 - 1) - blockIdx.x;   // longest blocks dispatch first
    const int bh = blockIdx.y;
    const int b  = bh >> 4;
    const int h  = bh & 15;
    const int qb = qt * 64;

    const int t    = threadIdx.x;
    const int wave = t >> 6;
    const int lane = t & 63;
    const int quad = lane >> 4;
    const int col  = lane & 15;

    const size_t bbase = (size_t)b * SEQ * DMODEL + (size_t)h * DHEAD;

    // --- Q fragments (A-operand, split hi/lo), loaded once from fp32 qh ---
    const int qm = qb + wave * 16 + col;          // this lane's A-row (m = col)
    f16x8 qhi[2], qlo[2];
    {
        const float* qp = qa + bbase + (size_t)qm * DMODEL + quad * 8;
#pragma unroll
        for (int kt = 0; kt < 2; kt++) {
            float4 x0 = *(const float4*)(qp + kt * 32);
            float4 x1 = *(const float4*)(qp + kt * 32 + 4);
            float xs[8] = {x0.x, x0.y, x0.z, x0.w, x1.x, x1.y, x1.z, x1.w};
#pragma unroll
            for (int j = 0; j < 8; j++) {
                _Float16 hi = (_Float16)xs[j];
                qhi[kt][j] = hi;
                qlo[kt][j] = (_Float16)(xs[j] - (float)hi);
            }
        }
    }

    const int srow = t >> 2;           // staging: 0..63 (key row)
    const int sdg  = (t & 3) << 4;     // staging: d-group 0,16,32,48

    float m_i[4], l_i[4];
    f32x4 o[4];
#pragma unroll
    for (int r = 0; r < 4; r++) { m_i[r] = -1e30f; l_i[r] = 0.f; }
#pragma unroll
    for (int dt = 0; dt < 4; dt++) o[dt] = (f32x4){0.f, 0.f, 0.f, 0.f};

    const int wq0 = qb + wave * 16;    // wave's first q row
    _Float16* Pw = &smem[P_OFF + wave * P_WAVE];

    for (int kb = 0; kb <= qb; kb += 64) {
        __syncthreads();               // previous tile's compute done

        // ---- stage K (fp32 -> f16 hi/lo) and V (bf16 -> f16, transposed) ----
        {
            const float* kp = kh + bbase + (size_t)(kb + srow) * DMODEL + sdg;
            f16x8 khiv[2], klov[2];
#pragma unroll
            for (int g = 0; g < 2; g++) {
                float4 x0 = *(const float4*)(kp + g * 8);
                float4 x1 = *(const float4*)(kp + g * 8 + 4);
                float xs[8] = {x0.x, x0.y, x0.z, x0.w, x1.x, x1.y, x1.z, x1.w};
#pragma unroll
                for (int j = 0; j < 8; j++) {
                    _Float16 hi = (_Float16)xs[j];
                    khiv[g][j] = hi;
                    klov[g][j] = (_Float16)(xs[j] - (float)hi);
                }
            }
            *(f16x8*)&smem[KHI_OFF + srow * LDS_STRIDE + sdg]     = khiv[0];
            *(f16x8*)&smem[KHI_OFF + srow * LDS_STRIDE + sdg + 8] = khiv[1];
            *(f16x8*)&smem[KLO_OFF + srow * LDS_STRIDE + sdg]     = klov[0];
            *(f16x8*)&smem[KLO_OFF + srow * LDS_STRIDE + sdg + 8] = klov[1];

            const unsigned int* vp =
                (const unsigned int*)(vh + bbase + (size_t)(kb + srow) * DMODEL + sdg);
            uint4 v0 = *(const uint4*)vp;
            uint4 v1 = *(const uint4*)(vp + 4);
            unsigned int vs[8] = {v0.x, v0.y, v0.z, v0.w, v1.x, v1.y, v1.z, v1.w};
#pragma unroll
            for (int j = 0; j < 8; j++) {
                float flo = __uint_as_float((vs[j] & 0xffffu) << 16);
                float fhi = __uint_as_float(vs[j] & 0xffff0000u);
                smem[VT_OFF + (sdg + 2 * j    ) * LDS_STRIDE + srow] = (_Float16)flo;
                smem[VT_OFF + (sdg + 2 * j + 1) * LDS_STRIDE + srow] = (_Float16)fhi;
            }
        }
        __syncthreads();               // staging visible to all waves

        if (kb > wq0 + 15) continue;   // tile fully masked for this wave (uniform)

        // ---- QK^T: 16q x 64keys, split-f16 ----
        f32x4 acc[4];
#pragma unroll
        for (int ct = 0; ct < 4; ct++) acc[ct] = (f32x4){0.f, 0.f, 0.f, 0.f};
#pragma unroll
        for (int kt = 0; kt < 2; kt++) {
#pragma unroll
            for (int ct = 0; ct < 4; ct++) {
                f16x8 bhi = *(f16x8*)&smem[KHI_OFF + (ct * 16 + col) * LDS_STRIDE + kt * 32 + quad * 8];
                f16x8 blo = *(f16x8*)&smem[KLO_OFF + (ct * 16 + col) * LDS_STRIDE + kt * 32 + quad * 8];
                acc[ct] = __builtin_amdgcn_mfma_f32_16x16x32_f16(qhi[kt], bhi, acc[ct], 0, 0, 0);
                acc[ct] = __builtin_amdgcn_mfma_f32_16x16x32_f16(qhi[kt], blo, acc[ct], 0, 0, 0);
                acc[ct] = __builtin_amdgcn_mfma_f32_16x16x32_f16(qlo[kt], bhi, acc[ct], 0, 0, 0);
            }
        }

        // ---- online softmax (C-layout: row=quad*4+r, col=lane&15+16*ct) ----
        const bool need_mask = (kb + 63 > wq0);   // wave-uniform
#pragma unroll
        for (int r = 0; r < 4; r++) {
            const int qrow = wq0 + quad * 4 + r;
            float s0 = acc[0][r], s1 = acc[1][r], s2 = acc[2][r], s3 = acc[3][r];
            if (need_mask) {
                s0 = (kb +  0 + col <= qrow) ? s0 : -1e30f;
                s1 = (kb + 16 + col <= qrow) ? s1 : -1e30f;
                s2 = (kb + 32 + col <= qrow) ? s2 : -1e30f;
                s3 = (kb + 48 + col <= qrow) ? s3 : -1e30f;
            }
            float rm = fmaxf(fmaxf(s0, s1), fmaxf(s2, s3));
#pragma unroll
            for (int off = 1; off <= 8; off <<= 1)
                rm = fmaxf(rm, __shfl_xor(rm, off, 64));
            const float mnew  = fmaxf(m_i[r], rm);
            const float alpha = __expf(m_i[r] - mnew);
            const float p0 = __expf(s0 - mnew), p1 = __expf(s1 - mnew);
            const float p2 = __expf(s2 - mnew), p3 = __expf(s3 - mnew);
            float rs = p0 + p1 + p2 + p3;
#pragma unroll
            for (int off = 1; off <= 8; off <<= 1)
                rs += __shfl_xor(rs, off, 64);
            l_i[r] = l_i[r] * alpha + rs;
            m_i[r] = mnew;
#pragma unroll
            for (int dt = 0; dt < 4; dt++) o[dt][r] *= alpha;
            const int prow = quad * 4 + r;
            Pw[prow * LDS_STRIDE + col     ] = (_Float16)p0;
            Pw[prow * LDS_STRIDE + col + 16] = (_Float16)p1;
            Pw[prow * LDS_STRIDE + col + 32] = (_Float16)p2;
            Pw[prow * LDS_STRIDE + col + 48] = (_Float16)p3;
        }

        // ---- PV: O += P(16x64) @ V(64x64), P via LDS (A-layout), Vt B-frags ----
#pragma unroll
        for (int kt = 0; kt < 2; kt++) {
            f16x8 a = *(f16x8*)&Pw[col * LDS_STRIDE + kt * 32 + quad * 8];
#pragma unroll
            for (int dt = 0; dt < 4; dt++) {
                f16x8 bv = *(f16x8*)&smem[VT_OFF + (dt * 16 + col) * LDS_STRIDE + kt * 32 + quad * 8];
                o[dt] = __builtin_amdgcn_mfma_f32_16x16x32_f16(a, bv, o[dt], 0, 0, 0);
            }
        }
    }

    // ---- epilogue: /l, /sqrt(64)=8, write att over qh (same rows, safe) ----
#pragma unroll
    for (int r = 0; r < 4; r++) {
        const float inv = 1.0f / (l_i[r] * 8.0f);
        const int q = wq0 + quad * 4 + r;
        float* op = qa + bbase + (size_t)q * DMODEL;
#pragma unroll
        for (int dt = 0; dt < 4; dt++)
            op[dt * 16 + col] = o[dt][r] * inv;
    }
}

// ---------------------------------------------------------------------------
// Launch. Inputs: q, k, v, mask(ignored), Wq, Wk, Wv, Wo — all fp32.
// qh,kh fp32 in ws (score path must stay fp32-accurate); vh bf16 in ws if it
// fits, else stored in d_out (fully consumed before the final GEMM overwrites).
// ---------------------------------------------------------------------------
extern "C" void kernel_launch(void* const* d_in, const int* in_sizes, int n_in,
                              void* d_out, int out_size, void* d_ws, size_t ws_size,
                              hipStream_t stream)
{
    const float* q  = (const float*)d_in[0];
    const float* k  = (const float*)d_in[1];
    const float* v  = (const float*)d_in[2];
    const float* Wq = (const float*)d_in[4];
    const float* Wk = (const float*)d_in[5];
    const float* Wv = (const float*)d_in[6];
    const float* Wo = (const float*)d_in[7];
    float* out = (float*)d_out;

    const int    M   = BATCH * SEQ;            // 4096
    const size_t npe = (size_t)M * DMODEL;

    dim3 gthreads(256);
    dim3 ggrid(DMODEL / 64, M / 64);
    dim3 agrid(SEQ / 64, BATCH * NHEAD);       // (32, 32), 256 threads each

    float* qh = (float*)d_ws;
    float* kh = qh + npe;
    __hip_bfloat16* vh = (ws_size >= 2 * npe * sizeof(float) + npe * sizeof(__hip_bfloat16))
                         ? (__hip_bfloat16*)(kh + npe)      // 40 MB tier
                         : (__hip_bfloat16*)d_out;          // 32 MB tier

    gemm_tiled<float, float, float><<<ggrid, gthreads, 0, stream>>>(q, Wq, qh, M, DMODEL, DMODEL);
    gemm_tiled<float, float, float><<<ggrid, gthreads, 0, stream>>>(k, Wk, kh, M, DMODEL, DMODEL);
    gemm_tiled<float, float, __hip_bfloat16><<<ggrid, gthreads, 0, stream>>>(v, Wv, vh, M, DMODEL, DMODEL);
    attn_mfma<<<agrid, gthreads, 0, stream>>>(qh, kh, vh);
    gemm_tiled<float, float, float><<<ggrid, gthreads, 0, stream>>>(qh, Wo, out, M, DMODEL, DMODEL);
}

// Round 5
// 454.946 us; speedup vs baseline: 9.7256x; 1.6871x over previous
//
#include <hip/hip_runtime.h>
#include <hip/hip_bf16.h>

// Problem constants (fixed by the reference)
#define BATCH  2
#define SEQ    2048
#define DMODEL 1024
#define NHEAD  16
#define DHEAD  64

typedef _Float16 f16x4 __attribute__((ext_vector_type(4)));
typedef _Float16 f16x8 __attribute__((ext_vector_type(8)));
typedef float    f32x4 __attribute__((ext_vector_type(4)));

union H16 { unsigned short u; _Float16 f; };
__device__ __forceinline__ _Float16 u2h(unsigned short u) { H16 c; c.u = u; return c.f; }
__device__ __forceinline__ unsigned short h2u(_Float16 f) { H16 c; c.f = f; return c.u; }

// ---------------------------------------------------------------------------
// MFMA GEMM: C[M,N] = A[M,K] @ B[K,N], fp32 input, fp32 accumulate.
// SPLIT=3: Markidis split-f16 (AhiBhi + AhiBlo + AloBhi) -> fp32-grade result.
// SPLIT=1: single f16 (rel err ~5e-4) for linear paths (V-proj, O-proj).
// B is pre-scaled x32 at staging (W ~ N(0,1/32): keeps f16 lo residuals out of
// denormal range, in case MFMA flushes them); epilogue multiplies by 1/32.
// BM=64, BN=128, BK=32; 256 threads = 4 waves, wave w owns n-quadrant w*32.
// LDS stride 40 halves (80 B) keeps ds_read_b128 16-B aligned.
// CT: unsigned (packed f16 hi|lo<<16), _Float16, or float.
// ---------------------------------------------------------------------------
template <int SPLIT, typename CT>
__global__ __launch_bounds__(256) void gemm_mfma(const float* __restrict__ A,
                                                 const float* __restrict__ B,
                                                 CT* __restrict__ C,
                                                 int N, int K)
{
    constexpr int AH  = 0;
    constexpr int AL  = 64 * 40;                                   // SPLIT==3 only
    constexpr int BH  = (SPLIT == 3) ? 2 * 64 * 40 : 64 * 40;
    constexpr int BL  = BH + 128 * 40;                             // SPLIT==3 only
    constexpr int TOT = (SPLIT == 3) ? (2 * 64 * 40 + 2 * 128 * 40)
                                     : (64 * 40 + 128 * 40);
    __shared__ __align__(16) _Float16 smem[TOT];

    const int m0   = blockIdx.x * 64;
    const int n0   = blockIdx.y * 128;
    const int t    = threadIdx.x;
    const int wave = t >> 6;
    const int lane = t & 63;
    const int quad = lane >> 4;
    const int col  = lane & 15;
    const int wn   = wave * 32;

    const int am  = t >> 2;            // A staging: row 0..63
    const int ak  = (t & 3) << 3;      // A staging: k offset 0,8,16,24
    const int bn  = t & 127;           // B staging: col 0..127
    const int bk0 = (t >> 7) << 4;     // B staging: k base 0 or 16

    const float* Ap = A + (size_t)(m0 + am) * K + ak;
    const float* Bp = B + (size_t)bk0 * N + n0 + bn;

    f32x4 acc[4][2];
#pragma unroll
    for (int mt = 0; mt < 4; mt++)
#pragma unroll
        for (int nt = 0; nt < 2; nt++) acc[mt][nt] = (f32x4){0.f, 0.f, 0.f, 0.f};

    f16x4 pah[2], pal[2], pbh[4], pbl[4];

    auto load_convert = [&](int k0) {
        float4 a0 = *(const float4*)(Ap + k0);
        float4 a1 = *(const float4*)(Ap + k0 + 4);
        float av[8] = {a0.x, a0.y, a0.z, a0.w, a1.x, a1.y, a1.z, a1.w};
#pragma unroll
        for (int g = 0; g < 2; g++)
#pragma unroll
            for (int j = 0; j < 4; j++) {
                float x = av[g * 4 + j];
                _Float16 h = (_Float16)x;
                pah[g][j] = h;
                if constexpr (SPLIT == 3) pal[g][j] = (_Float16)(x - (float)h);
            }
#pragma unroll
        for (int i = 0; i < 16; i++) {
            float x = Bp[(size_t)(k0 + i) * N] * 32.0f;   // scale: keep lo normal
            _Float16 h = (_Float16)x;
            pbh[i >> 2][i & 3] = h;
            if constexpr (SPLIT == 3) pbl[i >> 2][i & 3] = (_Float16)(x - (float)h);
        }
    };

    load_convert(0);

    for (int k0 = 0; k0 < K; k0 += 32) {
        __syncthreads();               // previous tile's frag reads done
#pragma unroll
        for (int g = 0; g < 2; g++) {
            *(f16x4*)&smem[AH + am * 40 + ak + 4 * g] = pah[g];
            if constexpr (SPLIT == 3) *(f16x4*)&smem[AL + am * 40 + ak + 4 * g] = pal[g];
        }
#pragma unroll
        for (int g = 0; g < 4; g++) {
            *(f16x4*)&smem[BH + bn * 40 + bk0 + 4 * g] = pbh[g];
            if constexpr (SPLIT == 3) *(f16x4*)&smem[BL + bn * 40 + bk0 + 4 * g] = pbl[g];
        }
        __syncthreads();               // staging visible

        if (k0 + 32 < K) load_convert(k0 + 32);   // prefetch next chunk into regs

        f16x8 a_h[4], a_l[4], b_h[2], b_l[2];
#pragma unroll
        for (int mt = 0; mt < 4; mt++) {
            a_h[mt] = *(f16x8*)&smem[AH + (mt * 16 + col) * 40 + quad * 8];
            if constexpr (SPLIT == 3)
                a_l[mt] = *(f16x8*)&smem[AL + (mt * 16 + col) * 40 + quad * 8];
        }
#pragma unroll
        for (int nt = 0; nt < 2; nt++) {
            b_h[nt] = *(f16x8*)&smem[BH + (wn + nt * 16 + col) * 40 + quad * 8];
            if constexpr (SPLIT == 3)
                b_l[nt] = *(f16x8*)&smem[BL + (wn + nt * 16 + col) * 40 + quad * 8];
        }
#pragma unroll
        for (int nt = 0; nt < 2; nt++)
#pragma unroll
            for (int mt = 0; mt < 4; mt++) {
                acc[mt][nt] = __builtin_amdgcn_mfma_f32_16x16x32_f16(a_h[mt], b_h[nt], acc[mt][nt], 0, 0, 0);
                if constexpr (SPLIT == 3) {
                    acc[mt][nt] = __builtin_amdgcn_mfma_f32_16x16x32_f16(a_h[mt], b_l[nt], acc[mt][nt], 0, 0, 0);
                    acc[mt][nt] = __builtin_amdgcn_mfma_f32_16x16x32_f16(a_l[mt], b_h[nt], acc[mt][nt], 0, 0, 0);
                }
            }
    }

    // epilogue: undo x32 B-scaling; C-layout row=quad*4+r, col=lane&15
    const float inv = 1.0f / 32.0f;
#pragma unroll
    for (int mt = 0; mt < 4; mt++)
#pragma unroll
        for (int nt = 0; nt < 2; nt++)
#pragma unroll
            for (int r = 0; r < 4; r++) {
                float val = acc[mt][nt][r] * inv;
                size_t idx = (size_t)(m0 + mt * 16 + quad * 4 + r) * N + n0 + wn + nt * 16 + col;
                if constexpr (SPLIT == 3) {   // packed split output (uint32)
                    _Float16 h = (_Float16)val;
                    _Float16 l = (_Float16)(val - (float)h);
                    C[idx] = (unsigned)h2u(h) | ((unsigned)h2u(l) << 16);
                } else if constexpr (__is_same(CT, _Float16)) {
                    C[idx] = (_Float16)val;
                } else {
                    C[idx] = val;
                }
            }
}

// ---------------------------------------------------------------------------
// MFMA flash attention (causal). Block = 64 queries x one (b,h); 4 waves x 16 q.
// Softmax on UNSCALED scores (reference quirk), /sqrt(64)=8 at the end.
// Q/K arrive as packed (f16hi | f16lo<<16) uint32 from the split GEMMs;
// V arrives as _Float16. att written as fp32 bits over the packed-Q buffer
// (identical addresses per block -> race-free aliasing, uint stores only).
// VT rows carry swizzle +((r>>4)&3)*16 halves: separates the 4 sdg write
// groups by 8 banks (conflict-free); a per-dt constant on the read side.
// ---------------------------------------------------------------------------
#define LDS_STRIDE 72
#define KHI_OFF 0
#define KLO_OFF (64 * LDS_STRIDE)                   // 4608
#define VT_OFF  (2 * 64 * LDS_STRIDE)               // 9216
#define VT_SIZE (64 * LDS_STRIDE + 64)              // 4672 (swizzle headroom)
#define P_OFF   (VT_OFF + VT_SIZE)                  // 13888
#define P_WAVE  (16 * LDS_STRIDE)
#define SMEM_HALVES (P_OFF + 4 * P_WAVE)            // 18496 = 36992 B

__global__ __launch_bounds__(256) void attn_mfma(unsigned* __restrict__ qa,   // packed qh in, f32-bits att out
                                                 const unsigned* __restrict__ kh,
                                                 const _Float16* __restrict__ vh)
{
    __shared__ __align__(16) _Float16 smem[SMEM_HALVES];

    const int qt = (SEQ / 64 - 1) - blockIdx.x;   // longest blocks first
    const int bh = blockIdx.y;
    const int b  = bh >> 4;
    const int h  = bh & 15;
    const int qb = qt * 64;

    const int t    = threadIdx.x;
    const int wave = t >> 6;
    const int lane = t & 63;
    const int quad = lane >> 4;
    const int col  = lane & 15;

    const size_t bbase = (size_t)b * SEQ * DMODEL + (size_t)h * DHEAD;
    const unsigned* kb_ptr = kh + bbase;
    const _Float16* vb_ptr = vh + bbase;

    // --- Q fragments (A-operand, hi/lo) from packed uint32 ---
    const int qm = qb + wave * 16 + col;
    f16x8 qhi[2], qlo[2];
    {
        const unsigned* qp = qa + bbase + (size_t)qm * DMODEL + quad * 8;
#pragma unroll
        for (int kt = 0; kt < 2; kt++) {
            uint4 u0 = *(const uint4*)(qp + kt * 32);
            uint4 u1 = *(const uint4*)(qp + kt * 32 + 4);
            unsigned us[8] = {u0.x, u0.y, u0.z, u0.w, u1.x, u1.y, u1.z, u1.w};
#pragma unroll
            for (int j = 0; j < 8; j++) {
                qhi[kt][j] = u2h((unsigned short)(us[j] & 0xffffu));
                qlo[kt][j] = u2h((unsigned short)(us[j] >> 16));
            }
        }
    }

    const int srow = t >> 2;           // staging: key row 0..63
    const int sdg  = (t & 3) << 4;     // staging: d-group 0,16,32,48
    const int vswz = (t & 3) * 16;     // VT bank swizzle (constant per thread)

    float m_i[4], l_i[4];
    f32x4 o[4];
#pragma unroll
    for (int r = 0; r < 4; r++) { m_i[r] = -1e30f; l_i[r] = 0.f; }
#pragma unroll
    for (int dt = 0; dt < 4; dt++) o[dt] = (f32x4){0.f, 0.f, 0.f, 0.f};

    const int wq0 = qb + wave * 16;
    _Float16* Pw = &smem[P_OFF + wave * P_WAVE];

    f16x8 pkhi[2], pklo[2], pv[2];
    auto load_tile = [&](int kb) {
        const unsigned* kp = kb_ptr + (size_t)(kb + srow) * DMODEL + sdg;
        uint4 u0 = *(const uint4*)(kp + 0);
        uint4 u1 = *(const uint4*)(kp + 4);
        uint4 u2 = *(const uint4*)(kp + 8);
        uint4 u3 = *(const uint4*)(kp + 12);
        unsigned us[16] = {u0.x, u0.y, u0.z, u0.w, u1.x, u1.y, u1.z, u1.w,
                           u2.x, u2.y, u2.z, u2.w, u3.x, u3.y, u3.z, u3.w};
#pragma unroll
        for (int g = 0; g < 2; g++)
#pragma unroll
            for (int j = 0; j < 8; j++) {
                pkhi[g][j] = u2h((unsigned short)(us[g * 8 + j] & 0xffffu));
                pklo[g][j] = u2h((unsigned short)(us[g * 8 + j] >> 16));
            }
        const _Float16* vp = vb_ptr + (size_t)(kb + srow) * DMODEL + sdg;
        pv[0] = *(const f16x8*)vp;
        pv[1] = *(const f16x8*)(vp + 8);
    };

    load_tile(0);

    for (int kb = 0; kb <= qb; kb += 64) {
        __syncthreads();               // previous tile's compute done

        *(f16x8*)&smem[KHI_OFF + srow * LDS_STRIDE + sdg]     = pkhi[0];
        *(f16x8*)&smem[KHI_OFF + srow * LDS_STRIDE + sdg + 8] = pkhi[1];
        *(f16x8*)&smem[KLO_OFF + srow * LDS_STRIDE + sdg]     = pklo[0];
        *(f16x8*)&smem[KLO_OFF + srow * LDS_STRIDE + sdg + 8] = pklo[1];
#pragma unroll
        for (int j = 0; j < 8; j++) {
            smem[VT_OFF + (sdg + j    ) * LDS_STRIDE + vswz + srow] = pv[0][j];
            smem[VT_OFF + (sdg + 8 + j) * LDS_STRIDE + vswz + srow] = pv[1][j];
        }
        __syncthreads();               // staging visible

        if (kb + 64 <= qb) load_tile(kb + 64);   // prefetch next tile into regs

        // ---- QK^T: 16q x 64keys, split-f16 (3 MFMAs) ----
        f32x4 acc[4];
#pragma unroll
        for (int ct = 0; ct < 4; ct++) acc[ct] = (f32x4){0.f, 0.f, 0.f, 0.f};
#pragma unroll
        for (int kt = 0; kt < 2; kt++) {
#pragma unroll
            for (int ct = 0; ct < 4; ct++) {
                f16x8 bhi = *(f16x8*)&smem[KHI_OFF + (ct * 16 + col) * LDS_STRIDE + kt * 32 + quad * 8];
                f16x8 blo = *(f16x8*)&smem[KLO_OFF + (ct * 16 + col) * LDS_STRIDE + kt * 32 + quad * 8];
                acc[ct] = __builtin_amdgcn_mfma_f32_16x16x32_f16(qhi[kt], bhi, acc[ct], 0, 0, 0);
                acc[ct] = __builtin_amdgcn_mfma_f32_16x16x32_f16(qhi[kt], blo, acc[ct], 0, 0, 0);
                acc[ct] = __builtin_amdgcn_mfma_f32_16x16x32_f16(qlo[kt], bhi, acc[ct], 0, 0, 0);
            }
        }

        // ---- online softmax (C-layout: row=quad*4+r, col=lane&15+16*ct) ----
        const bool need_mask = (kb + 63 > wq0);   // wave-uniform
#pragma unroll
        for (int r = 0; r < 4; r++) {
            const int qrow = wq0 + quad * 4 + r;
            float s0 = acc[0][r], s1 = acc[1][r], s2 = acc[2][r], s3 = acc[3][r];
            if (need_mask) {
                s0 = (kb +  0 + col <= qrow) ? s0 : -1e30f;
                s1 = (kb + 16 + col <= qrow) ? s1 : -1e30f;
                s2 = (kb + 32 + col <= qrow) ? s2 : -1e30f;
                s3 = (kb + 48 + col <= qrow) ? s3 : -1e30f;
            }
            float rm = fmaxf(fmaxf(s0, s1), fmaxf(s2, s3));
#pragma unroll
            for (int off = 1; off <= 8; off <<= 1)
                rm = fmaxf(rm, __shfl_xor(rm, off, 64));
            const float mnew  = fmaxf(m_i[r], rm);
            const float alpha = __expf(m_i[r] - mnew);
            const float p0 = __expf(s0 - mnew), p1 = __expf(s1 - mnew);
            const float p2 = __expf(s2 - mnew), p3 = __expf(s3 - mnew);
            float rs = p0 + p1 + p2 + p3;
#pragma unroll
            for (int off = 1; off <= 8; off <<= 1)
                rs += __shfl_xor(rs, off, 64);
            l_i[r] = l_i[r] * alpha + rs;
            m_i[r] = mnew;
#pragma unroll
            for (int dt = 0; dt < 4; dt++) o[dt][r] *= alpha;
            const int prow = quad * 4 + r;
            Pw[prow * LDS_STRIDE + col     ] = (_Float16)p0;
            Pw[prow * LDS_STRIDE + col + 16] = (_Float16)p1;
            Pw[prow * LDS_STRIDE + col + 32] = (_Float16)p2;
            Pw[prow * LDS_STRIDE + col + 48] = (_Float16)p3;
        }

        // ---- PV: O += P(16x64) @ V(64x64); VT read uses per-dt swizzle const ----
#pragma unroll
        for (int kt = 0; kt < 2; kt++) {
            f16x8 a = *(f16x8*)&Pw[col * LDS_STRIDE + kt * 32 + quad * 8];
#pragma unroll
            for (int dt = 0; dt < 4; dt++) {
                f16x8 bv = *(f16x8*)&smem[VT_OFF + (dt * 16 + col) * LDS_STRIDE + (dt & 3) * 16 + kt * 32 + quad * 8];
                o[dt] = __builtin_amdgcn_mfma_f32_16x16x32_f16(a, bv, o[dt], 0, 0, 0);
            }
        }
    }

    // ---- epilogue: /l, /8; write att (fp32 bits) over packed qh — same addrs ----
#pragma unroll
    for (int r = 0; r < 4; r++) {
        const float inv = 1.0f / (l_i[r] * 8.0f);
        const int q = wq0 + quad * 4 + r;
        unsigned* op = qa + bbase + (size_t)q * DMODEL;
#pragma unroll
        for (int dt = 0; dt < 4; dt++)
            op[dt * 16 + col] = __float_as_uint(o[dt][r] * inv);
    }
}

// ---------------------------------------------------------------------------
// Launch. Inputs: q, k, v, mask(ignored), Wq, Wk, Wv, Wo — all fp32.
// qh/kh: packed split-f16 (uint32) in ws (16 MB each). vh: _Float16, in ws if
// it fits (40 MB tier) else in d_out (consumed by attention before the final
// GEMM overwrites d_out). att: fp32 in qh's buffer (address-identical alias).
// ---------------------------------------------------------------------------
extern "C" void kernel_launch(void* const* d_in, const int* in_sizes, int n_in,
                              void* d_out, int out_size, void* d_ws, size_t ws_size,
                              hipStream_t stream)
{
    const float* q  = (const float*)d_in[0];
    const float* k  = (const float*)d_in[1];
    const float* v  = (const float*)d_in[2];
    const float* Wq = (const float*)d_in[4];
    const float* Wk = (const float*)d_in[5];
    const float* Wv = (const float*)d_in[6];
    const float* Wo = (const float*)d_in[7];
    float* out = (float*)d_out;

    const int    M   = BATCH * SEQ;            // 4096
    const size_t npe = (size_t)M * DMODEL;     // 4,194,304

    unsigned* qh = (unsigned*)d_ws;
    unsigned* kh = qh + npe;
    _Float16* vh = (ws_size >= 2 * npe * sizeof(unsigned) + npe * sizeof(_Float16))
                   ? (_Float16*)(kh + npe)     // 40 MB tier
                   : (_Float16*)d_out;         // 32 MB tier

    dim3 gblock(256);
    dim3 ggrid(M / 64, DMODEL / 128);          // (64, 8) = 512 blocks
    dim3 agrid(SEQ / 64, BATCH * NHEAD);       // (32, 32)

    gemm_mfma<3, unsigned><<<ggrid, gblock, 0, stream>>>(q, Wq, qh, DMODEL, DMODEL);
    gemm_mfma<3, unsigned><<<ggrid, gblock, 0, stream>>>(k, Wk, kh, DMODEL, DMODEL);
    gemm_mfma<1, _Float16><<<ggrid, gblock, 0, stream>>>(v, Wv, vh, DMODEL, DMODEL);
    attn_mfma<<<agrid, gblock, 0, stream>>>(qh, kh, vh);
    gemm_mfma<1, float><<<ggrid, gblock, 0, stream>>>((const float*)qh, Wo, out, DMODEL, DMODEL);
}

// Round 6
// 378.092 us; speedup vs baseline: 11.7026x; 1.2033x over previous
//
#include <hip/hip_runtime.h>
#include <hip/hip_bf16.h>

// Problem constants (fixed by the reference)
#define BATCH  2
#define SEQ    2048
#define DMODEL 1024
#define NHEAD  16
#define DHEAD  64

typedef _Float16 f16x4 __attribute__((ext_vector_type(4)));
typedef _Float16 f16x8 __attribute__((ext_vector_type(8)));
typedef float    f32x4 __attribute__((ext_vector_type(4)));

union H16 { unsigned short u; _Float16 f; };
__device__ __forceinline__ _Float16 u2h(unsigned short u) { H16 c; c.u = u; return c.f; }
__device__ __forceinline__ unsigned short h2u(_Float16 f) { H16 c; c.f = f; return c.u; }

// ---------------------------------------------------------------------------
// Weight pack: P[i] = (f16(32*W[i]) | f16(32*W[i] - hi) << 16).
// x32 scale keeps the lo residuals of W ~ N(0,1/32) out of f16 denormal range;
// GEMM epilogue multiplies by 1/32. 1024x1024 fp32 -> 1M u32 (4 MB).
// ---------------------------------------------------------------------------
__global__ __launch_bounds__(256) void pack_w2(const float* __restrict__ W0,
                                               const float* __restrict__ W1,
                                               unsigned* __restrict__ P0,
                                               unsigned* __restrict__ P1)
{
    const float* W = blockIdx.y ? W1 : W0;
    unsigned*    P = blockIdx.y ? P1 : P0;
    const int i = blockIdx.x * 256 + threadIdx.x;      // x4 elems
    float4 x = ((const float4*)W)[i];
    float xs[4] = {x.x, x.y, x.z, x.w};
    unsigned out[4];
#pragma unroll
    for (int j = 0; j < 4; j++) {
        float s = xs[j] * 32.0f;
        _Float16 h = (_Float16)s;
        _Float16 l = (_Float16)(s - (float)h);
        out[j] = (unsigned)h2u(h) | ((unsigned)h2u(l) << 16);
    }
    ((uint4*)P)[i] = make_uint4(out[0], out[1], out[2], out[3]);
}

__global__ __launch_bounds__(256) void pack_w1(const float* __restrict__ W,
                                               unsigned* __restrict__ P)
{
    const int i = blockIdx.x * 256 + threadIdx.x;
    float4 x = ((const float4*)W)[i];
    float xs[4] = {x.x, x.y, x.z, x.w};
    unsigned out[4];
#pragma unroll
    for (int j = 0; j < 4; j++) {
        float s = xs[j] * 32.0f;
        _Float16 h = (_Float16)s;
        _Float16 l = (_Float16)(s - (float)h);
        out[j] = (unsigned)h2u(h) | ((unsigned)h2u(l) << 16);
    }
    ((uint4*)P)[i] = make_uint4(out[0], out[1], out[2], out[3]);
}

// ---------------------------------------------------------------------------
// MFMA GEMM: C[M,N] = A[M,K] @ Bpacked[K,N], fp32 A, pre-packed split-f16 B.
// SPLIT=3: Markidis (AhiBhi + AhiBlo + AloBhi) -> fp32-grade. SPLIT=1: hi only.
// B staging is now pure bit-unpack (2 ops/elem, was 5 fp ops).
// BM=64, BN=128, BK=32; 256 threads = 4 waves; LDS stride 40 halves.
// ---------------------------------------------------------------------------
template <int SPLIT, typename CT>
__global__ __launch_bounds__(256) void gemm_mfma(const float* __restrict__ A,
                                                 const unsigned* __restrict__ B,
                                                 CT* __restrict__ C,
                                                 int N, int K)
{
    constexpr int AH  = 0;
    constexpr int AL  = 64 * 40;
    constexpr int BH  = (SPLIT == 3) ? 2 * 64 * 40 : 64 * 40;
    constexpr int BL  = BH + 128 * 40;
    constexpr int TOT = (SPLIT == 3) ? (2 * 64 * 40 + 2 * 128 * 40)
                                     : (64 * 40 + 128 * 40);
    __shared__ __align__(16) _Float16 smem[TOT];

    const int m0   = blockIdx.x * 64;
    const int n0   = blockIdx.y * 128;
    const int t    = threadIdx.x;
    const int wave = t >> 6;
    const int lane = t & 63;
    const int quad = lane >> 4;
    const int col  = lane & 15;
    const int wn   = wave * 32;

    const int am  = t >> 2;            // A staging: row 0..63
    const int ak  = (t & 3) << 3;      // A staging: k offset 0,8,16,24
    const int bn  = t & 127;           // B staging: col 0..127
    const int bk0 = (t >> 7) << 4;     // B staging: k base 0 or 16

    const float*    Ap = A + (size_t)(m0 + am) * K + ak;
    const unsigned* Bp = B + (size_t)bk0 * N + n0 + bn;

    f32x4 acc[4][2];
#pragma unroll
    for (int mt = 0; mt < 4; mt++)
#pragma unroll
        for (int nt = 0; nt < 2; nt++) acc[mt][nt] = (f32x4){0.f, 0.f, 0.f, 0.f};

    f16x4 pah[2], pal[2], pbh[4], pbl[4];

    auto load_convert = [&](int k0) {
        float4 a0 = *(const float4*)(Ap + k0);
        float4 a1 = *(const float4*)(Ap + k0 + 4);
        float av[8] = {a0.x, a0.y, a0.z, a0.w, a1.x, a1.y, a1.z, a1.w};
#pragma unroll
        for (int g = 0; g < 2; g++)
#pragma unroll
            for (int j = 0; j < 4; j++) {
                float x = av[g * 4 + j];
                _Float16 h = (_Float16)x;
                pah[g][j] = h;
                if constexpr (SPLIT == 3) pal[g][j] = (_Float16)(x - (float)h);
            }
#pragma unroll
        for (int i = 0; i < 16; i++) {
            unsigned u = Bp[(size_t)(k0 + i) * N];
            pbh[i >> 2][i & 3] = u2h((unsigned short)(u & 0xffffu));
            if constexpr (SPLIT == 3) pbl[i >> 2][i & 3] = u2h((unsigned short)(u >> 16));
        }
    };

    load_convert(0);

    for (int k0 = 0; k0 < K; k0 += 32) {
        __syncthreads();
#pragma unroll
        for (int g = 0; g < 2; g++) {
            *(f16x4*)&smem[AH + am * 40 + ak + 4 * g] = pah[g];
            if constexpr (SPLIT == 3) *(f16x4*)&smem[AL + am * 40 + ak + 4 * g] = pal[g];
        }
#pragma unroll
        for (int g = 0; g < 4; g++) {
            *(f16x4*)&smem[BH + bn * 40 + bk0 + 4 * g] = pbh[g];
            if constexpr (SPLIT == 3) *(f16x4*)&smem[BL + bn * 40 + bk0 + 4 * g] = pbl[g];
        }
        __syncthreads();

        if (k0 + 32 < K) load_convert(k0 + 32);

        f16x8 a_h[4], a_l[4], b_h[2], b_l[2];
#pragma unroll
        for (int mt = 0; mt < 4; mt++) {
            a_h[mt] = *(f16x8*)&smem[AH + (mt * 16 + col) * 40 + quad * 8];
            if constexpr (SPLIT == 3)
                a_l[mt] = *(f16x8*)&smem[AL + (mt * 16 + col) * 40 + quad * 8];
        }
#pragma unroll
        for (int nt = 0; nt < 2; nt++) {
            b_h[nt] = *(f16x8*)&smem[BH + (wn + nt * 16 + col) * 40 + quad * 8];
            if constexpr (SPLIT == 3)
                b_l[nt] = *(f16x8*)&smem[BL + (wn + nt * 16 + col) * 40 + quad * 8];
        }
#pragma unroll
        for (int nt = 0; nt < 2; nt++)
#pragma unroll
            for (int mt = 0; mt < 4; mt++) {
                acc[mt][nt] = __builtin_amdgcn_mfma_f32_16x16x32_f16(a_h[mt], b_h[nt], acc[mt][nt], 0, 0, 0);
                if constexpr (SPLIT == 3) {
                    acc[mt][nt] = __builtin_amdgcn_mfma_f32_16x16x32_f16(a_h[mt], b_l[nt], acc[mt][nt], 0, 0, 0);
                    acc[mt][nt] = __builtin_amdgcn_mfma_f32_16x16x32_f16(a_l[mt], b_h[nt], acc[mt][nt], 0, 0, 0);
                }
            }
    }

    const float inv = 1.0f / 32.0f;    // undo pack-time x32 B scaling
#pragma unroll
    for (int mt = 0; mt < 4; mt++)
#pragma unroll
        for (int nt = 0; nt < 2; nt++)
#pragma unroll
            for (int r = 0; r < 4; r++) {
                float val = acc[mt][nt][r] * inv;
                size_t idx = (size_t)(m0 + mt * 16 + quad * 4 + r) * N + n0 + wn + nt * 16 + col;
                if constexpr (SPLIT == 3) {
                    _Float16 h = (_Float16)val;
                    _Float16 l = (_Float16)(val - (float)h);
                    C[idx] = (unsigned)h2u(h) | ((unsigned)h2u(l) << 16);
                } else if constexpr (__is_same(CT, _Float16)) {
                    C[idx] = (_Float16)val;
                } else {
                    C[idx] = val;
                }
            }
}

// ---------------------------------------------------------------------------
// MFMA flash attention (causal), XCD-pinned block mapping.
// 1D grid of 1024; xcd = i&7 (round-robin dispatch heuristic); each XCD owns
// 4 (b,h) pairs -> K+V working set 4 x 768 KB = 3 MB, fits the 4 MB per-XCD L2.
// qt descending within each XCD (longest k-ranges first for load balance).
// Softmax on UNSCALED scores (reference quirk), /sqrt(64)=8 at the end.
// ---------------------------------------------------------------------------
#define LDS_STRIDE 72
#define KHI_OFF 0
#define KLO_OFF (64 * LDS_STRIDE)
#define VT_OFF  (2 * 64 * LDS_STRIDE)
#define VT_SIZE (64 * LDS_STRIDE + 64)
#define P_OFF   (VT_OFF + VT_SIZE)
#define P_WAVE  (16 * LDS_STRIDE)
#define SMEM_HALVES (P_OFF + 4 * P_WAVE)

__global__ __launch_bounds__(256) void attn_mfma(unsigned* __restrict__ qa,
                                                 const unsigned* __restrict__ kh,
                                                 const _Float16* __restrict__ vh)
{
    __shared__ __align__(16) _Float16 smem[SMEM_HALVES];

    const int i  = blockIdx.x;               // 0..1023
    const int j  = i >> 3;
    const int bh = (i & 7) + ((j & 3) << 3); // pin (b,h) to XCD i&7
    const int qt = (SEQ / 64 - 1) - (j >> 2);
    const int b  = bh >> 4;
    const int h  = bh & 15;
    const int qb = qt * 64;

    const int t    = threadIdx.x;
    const int wave = t >> 6;
    const int lane = t & 63;
    const int quad = lane >> 4;
    const int col  = lane & 15;

    const size_t bbase = (size_t)b * SEQ * DMODEL + (size_t)h * DHEAD;
    const unsigned* kb_ptr = kh + bbase;
    const _Float16* vb_ptr = vh + bbase;

    // --- Q fragments (A-operand, hi/lo) from packed uint32 ---
    const int qm = qb + wave * 16 + col;
    f16x8 qhi[2], qlo[2];
    {
        const unsigned* qp = qa + bbase + (size_t)qm * DMODEL + quad * 8;
#pragma unroll
        for (int kt = 0; kt < 2; kt++) {
            uint4 u0 = *(const uint4*)(qp + kt * 32);
            uint4 u1 = *(const uint4*)(qp + kt * 32 + 4);
            unsigned us[8] = {u0.x, u0.y, u0.z, u0.w, u1.x, u1.y, u1.z, u1.w};
#pragma unroll
            for (int jj = 0; jj < 8; jj++) {
                qhi[kt][jj] = u2h((unsigned short)(us[jj] & 0xffffu));
                qlo[kt][jj] = u2h((unsigned short)(us[jj] >> 16));
            }
        }
    }

    const int srow = t >> 2;           // staging: key row 0..63
    const int sdg  = (t & 3) << 4;     // staging: d-group 0,16,32,48
    const int vswz = (t & 3) * 16;     // VT bank swizzle

    float m_i[4], l_i[4];
    f32x4 o[4];
#pragma unroll
    for (int r = 0; r < 4; r++) { m_i[r] = -1e30f; l_i[r] = 0.f; }
#pragma unroll
    for (int dt = 0; dt < 4; dt++) o[dt] = (f32x4){0.f, 0.f, 0.f, 0.f};

    const int wq0 = qb + wave * 16;
    _Float16* Pw = &smem[P_OFF + wave * P_WAVE];

    f16x8 pkhi[2], pklo[2], pv[2];
    auto load_tile = [&](int kb) {
        const unsigned* kp = kb_ptr + (size_t)(kb + srow) * DMODEL + sdg;
        uint4 u0 = *(const uint4*)(kp + 0);
        uint4 u1 = *(const uint4*)(kp + 4);
        uint4 u2 = *(const uint4*)(kp + 8);
        uint4 u3 = *(const uint4*)(kp + 12);
        unsigned us[16] = {u0.x, u0.y, u0.z, u0.w, u1.x, u1.y, u1.z, u1.w,
                           u2.x, u2.y, u2.z, u2.w, u3.x, u3.y, u3.z, u3.w};
#pragma unroll
        for (int g = 0; g < 2; g++)
#pragma unroll
            for (int jj = 0; jj < 8; jj++) {
                pkhi[g][jj] = u2h((unsigned short)(us[g * 8 + jj] & 0xffffu));
                pklo[g][jj] = u2h((unsigned short)(us[g * 8 + jj] >> 16));
            }
        const _Float16* vp = vb_ptr + (size_t)(kb + srow) * DMODEL + sdg;
        pv[0] = *(const f16x8*)vp;
        pv[1] = *(const f16x8*)(vp + 8);
    };

    load_tile(0);

    for (int kb = 0; kb <= qb; kb += 64) {
        __syncthreads();

        *(f16x8*)&smem[KHI_OFF + srow * LDS_STRIDE + sdg]     = pkhi[0];
        *(f16x8*)&smem[KHI_OFF + srow * LDS_STRIDE + sdg + 8] = pkhi[1];
        *(f16x8*)&smem[KLO_OFF + srow * LDS_STRIDE + sdg]     = pklo[0];
        *(f16x8*)&smem[KLO_OFF + srow * LDS_STRIDE + sdg + 8] = pklo[1];
#pragma unroll
        for (int jj = 0; jj < 8; jj++) {
            smem[VT_OFF + (sdg + jj    ) * LDS_STRIDE + vswz + srow] = pv[0][jj];
            smem[VT_OFF + (sdg + 8 + jj) * LDS_STRIDE + vswz + srow] = pv[1][jj];
        }
        __syncthreads();

        if (kb + 64 <= qb) load_tile(kb + 64);

        if (kb > wq0 + 15) continue;   // fully masked for this wave (uniform)

        // ---- QK^T: 16q x 64keys, split-f16 (3 MFMAs) ----
        f32x4 acc[4];
#pragma unroll
        for (int ct = 0; ct < 4; ct++) acc[ct] = (f32x4){0.f, 0.f, 0.f, 0.f};
#pragma unroll
        for (int kt = 0; kt < 2; kt++) {
#pragma unroll
            for (int ct = 0; ct < 4; ct++) {
                f16x8 bhi = *(f16x8*)&smem[KHI_OFF + (ct * 16 + col) * LDS_STRIDE + kt * 32 + quad * 8];
                f16x8 blo = *(f16x8*)&smem[KLO_OFF + (ct * 16 + col) * LDS_STRIDE + kt * 32 + quad * 8];
                acc[ct] = __builtin_amdgcn_mfma_f32_16x16x32_f16(qhi[kt], bhi, acc[ct], 0, 0, 0);
                acc[ct] = __builtin_amdgcn_mfma_f32_16x16x32_f16(qhi[kt], blo, acc[ct], 0, 0, 0);
                acc[ct] = __builtin_amdgcn_mfma_f32_16x16x32_f16(qlo[kt], bhi, acc[ct], 0, 0, 0);
            }
        }

        // ---- online softmax (C-layout: row=quad*4+r, col=lane&15+16*ct) ----
        const bool need_mask = (kb + 63 > wq0);
#pragma unroll
        for (int r = 0; r < 4; r++) {
            const int qrow = wq0 + quad * 4 + r;
            float s0 = acc[0][r], s1 = acc[1][r], s2 = acc[2][r], s3 = acc[3][r];
            if (need_mask) {
                s0 = (kb +  0 + col <= qrow) ? s0 : -1e30f;
                s1 = (kb + 16 + col <= qrow) ? s1 : -1e30f;
                s2 = (kb + 32 + col <= qrow) ? s2 : -1e30f;
                s3 = (kb + 48 + col <= qrow) ? s3 : -1e30f;
            }
            float rm = fmaxf(fmaxf(s0, s1), fmaxf(s2, s3));
#pragma unroll
            for (int off = 1; off <= 8; off <<= 1)
                rm = fmaxf(rm, __shfl_xor(rm, off, 64));
            const float mnew  = fmaxf(m_i[r], rm);
            const float alpha = __expf(m_i[r] - mnew);
            const float p0 = __expf(s0 - mnew), p1 = __expf(s1 - mnew);
            const float p2 = __expf(s2 - mnew), p3 = __expf(s3 - mnew);
            float rs = p0 + p1 + p2 + p3;
#pragma unroll
            for (int off = 1; off <= 8; off <<= 1)
                rs += __shfl_xor(rs, off, 64);
            l_i[r] = l_i[r] * alpha + rs;
            m_i[r] = mnew;
#pragma unroll
            for (int dt = 0; dt < 4; dt++) o[dt][r] *= alpha;
            const int prow = quad * 4 + r;
            Pw[prow * LDS_STRIDE + col     ] = (_Float16)p0;
            Pw[prow * LDS_STRIDE + col + 16] = (_Float16)p1;
            Pw[prow * LDS_STRIDE + col + 32] = (_Float16)p2;
            Pw[prow * LDS_STRIDE + col + 48] = (_Float16)p3;
        }

        // ---- PV: O += P(16x64) @ V(64x64) ----
#pragma unroll
        for (int kt = 0; kt < 2; kt++) {
            f16x8 a = *(f16x8*)&Pw[col * LDS_STRIDE + kt * 32 + quad * 8];
#pragma unroll
            for (int dt = 0; dt < 4; dt++) {
                f16x8 bv = *(f16x8*)&smem[VT_OFF + (dt * 16 + col) * LDS_STRIDE + (dt & 3) * 16 + kt * 32 + quad * 8];
                o[dt] = __builtin_amdgcn_mfma_f32_16x16x32_f16(a, bv, o[dt], 0, 0, 0);
            }
        }
    }

    // ---- epilogue: /l, /8; write att (fp32 bits) over packed qh ----
#pragma unroll
    for (int r = 0; r < 4; r++) {
        const float inv = 1.0f / (l_i[r] * 8.0f);
        const int q = wq0 + quad * 4 + r;
        unsigned* op = qa + bbase + (size_t)q * DMODEL;
#pragma unroll
        for (int dt = 0; dt < 4; dt++)
            op[dt * 16 + col] = __float_as_uint(o[dt][r] * inv);
    }
}

// ---------------------------------------------------------------------------
// Launch. Inputs: q, k, v, mask(ignored), Wq, Wk, Wv, Wo — all fp32.
// Scratch choreography (ws >= 32 MB; d_out = 16 MB rotating scratch):
//   1. pack Wq -> d_out[0,4MB), Wk -> d_out[4,8)
//   2. gemm3 q@WqP -> qh (ws[0,16))          [WqP dead after]
//   3. pack Wv -> d_out[0,4)
//   4. gemm3 k@WkP -> kh (ws[16,32))         [WkP dead after]
//   5. gemm1 v@WvP -> vh = d_out[8,16) f16   [WvP dead after]
//   6. attn(qh,kh,vh) -> att over qh         [vh dead after]
//   7. pack Wo -> kh region (dead)
//   8. gemm1 att@WoP -> out = d_out[0,16)
// ---------------------------------------------------------------------------
extern "C" void kernel_launch(void* const* d_in, const int* in_sizes, int n_in,
                              void* d_out, int out_size, void* d_ws, size_t ws_size,
                              hipStream_t stream)
{
    const float* q  = (const float*)d_in[0];
    const float* k  = (const float*)d_in[1];
    const float* v  = (const float*)d_in[2];
    const float* Wq = (const float*)d_in[4];
    const float* Wk = (const float*)d_in[5];
    const float* Wv = (const float*)d_in[6];
    const float* Wo = (const float*)d_in[7];
    float* out = (float*)d_out;

    const int    M   = BATCH * SEQ;            // 4096
    const size_t npe = (size_t)M * DMODEL;     // 4,194,304
    const size_t nw  = (size_t)DMODEL * DMODEL;// 1,048,576

    unsigned* qh  = (unsigned*)d_ws;                 // 16 MB
    unsigned* kh  = qh + npe;                        // 16 MB
    unsigned* WqP = (unsigned*)d_out;                // [0,4)
    unsigned* WkP = WqP + nw;                        // [4,8)
    unsigned* WvP = (unsigned*)d_out;                // [0,4) after WqP dead
    _Float16* vh  = (_Float16*)((char*)d_out + 8u * 1024 * 1024);  // [8,16)
    unsigned* WoP = kh;                              // kh region after attn

    dim3 b256(256);
    dim3 pgrid(DMODEL * DMODEL / 1024, 2);     // pack: 4 elems/thread
    dim3 pgrid1(DMODEL * DMODEL / 1024);
    dim3 ggrid(M / 64, DMODEL / 128);          // (64, 8)
    dim3 agrid(1024);                          // XCD-pinned 1D

    pack_w2<<<pgrid, b256, 0, stream>>>(Wq, Wk, WqP, WkP);
    gemm_mfma<3, unsigned><<<ggrid, b256, 0, stream>>>(q, WqP, qh, DMODEL, DMODEL);
    pack_w1<<<pgrid1, b256, 0, stream>>>(Wv, WvP);
    gemm_mfma<3, unsigned><<<ggrid, b256, 0, stream>>>(k, WkP, kh, DMODEL, DMODEL);
    gemm_mfma<1, _Float16><<<ggrid, b256, 0, stream>>>(v, WvP, vh, DMODEL, DMODEL);
    attn_mfma<<<agrid, b256, 0, stream>>>(qh, kh, vh);
    pack_w1<<<pgrid1, b256, 0, stream>>>(Wo, WoP);
    gemm_mfma<1, float><<<ggrid, b256, 0, stream>>>((const float*)qh, WoP, out, DMODEL, DMODEL);
}

// Round 7
// 359.153 us; speedup vs baseline: 12.3197x; 1.0527x over previous
//
#include <hip/hip_runtime.h>
#include <hip/hip_bf16.h>

// Problem constants (fixed by the reference)
#define BATCH  2
#define SEQ    2048
#define DMODEL 1024
#define NHEAD  16
#define DHEAD  64

typedef _Float16 f16x4 __attribute__((ext_vector_type(4)));
typedef _Float16 f16x8 __attribute__((ext_vector_type(8)));
typedef float    f32x4 __attribute__((ext_vector_type(4)));

union H16 { unsigned short u; _Float16 f; };
__device__ __forceinline__ _Float16 u2h(unsigned short u) { H16 c; c.u = u; return c.f; }
__device__ __forceinline__ unsigned short h2u(_Float16 f) { H16 c; c.f = f; return c.u; }

// ---------------------------------------------------------------------------
// Weight pack: P[i] = (f16(32*W[i]) | f16(32*W[i] - hi) << 16).
// One launch packs Wq, Wk, Wv (blockIdx.y).
// ---------------------------------------------------------------------------
__device__ __forceinline__ void pack_body(const float* __restrict__ W,
                                          unsigned* __restrict__ P)
{
    const int i = blockIdx.x * 256 + threadIdx.x;      // x4 elems
    float4 x = ((const float4*)W)[i];
    float xs[4] = {x.x, x.y, x.z, x.w};
    unsigned out[4];
#pragma unroll
    for (int j = 0; j < 4; j++) {
        float s = xs[j] * 32.0f;
        _Float16 h = (_Float16)s;
        _Float16 l = (_Float16)(s - (float)h);
        out[j] = (unsigned)h2u(h) | ((unsigned)h2u(l) << 16);
    }
    ((uint4*)P)[i] = make_uint4(out[0], out[1], out[2], out[3]);
}

__global__ __launch_bounds__(256) void pack_w3(const float* __restrict__ W0,
                                               const float* __restrict__ W1,
                                               const float* __restrict__ W2,
                                               unsigned* __restrict__ P0,
                                               unsigned* __restrict__ P1,
                                               unsigned* __restrict__ P2)
{
    const float* W = (blockIdx.y == 0) ? W0 : (blockIdx.y == 1) ? W1 : W2;
    unsigned*    P = (blockIdx.y == 0) ? P0 : (blockIdx.y == 1) ? P1 : P2;
    pack_body(W, P);
}

__global__ __launch_bounds__(256) void pack_w1(const float* __restrict__ W,
                                               unsigned* __restrict__ P)
{
    pack_body(W, P);
}

// ---------------------------------------------------------------------------
// MFMA GEMM: C[M,N] = A[M,K] @ Bpacked[K,N], fp32 A, pre-packed split-f16 B.
// SPLIT=3: Markidis (AhiBhi + AhiBlo + AloBhi) -> fp32-grade. SPLIT=1: hi only.
// blockIdx.z selects one of two (A,B,C) triples -> Q and K projections run as
// ONE launch (1024 blocks, ~4/CU: cross-block latency hiding for the strided
// B loads the 2-barrier loop otherwise exposes).
// BM=64, BN=128, BK=32; 256 threads = 4 waves; LDS stride 40 halves.
// B global loads: 8x uint2 per thread (was 16x dword).
// ---------------------------------------------------------------------------
template <int SPLIT, typename CT>
__global__ __launch_bounds__(256) void gemm_mfma(const float* __restrict__ A0,
                                                 const float* __restrict__ A1,
                                                 const unsigned* __restrict__ B0,
                                                 const unsigned* __restrict__ B1,
                                                 CT* __restrict__ C0,
                                                 CT* __restrict__ C1,
                                                 int N, int K)
{
    constexpr int AH  = 0;
    constexpr int AL  = 64 * 40;
    constexpr int BH  = (SPLIT == 3) ? 2 * 64 * 40 : 64 * 40;
    constexpr int BL  = BH + 128 * 40;
    constexpr int TOT = (SPLIT == 3) ? (2 * 64 * 40 + 2 * 128 * 40)
                                     : (64 * 40 + 128 * 40);
    __shared__ __align__(16) _Float16 smem[TOT];

    const float*    A = blockIdx.z ? A1 : A0;
    const unsigned* B = blockIdx.z ? B1 : B0;
    CT*             C = blockIdx.z ? C1 : C0;

    const int m0   = blockIdx.x * 64;
    const int n0   = blockIdx.y * 128;
    const int t    = threadIdx.x;
    const int wave = t >> 6;
    const int lane = t & 63;
    const int quad = lane >> 4;
    const int col  = lane & 15;
    const int wn   = wave * 32;

    const int am  = t >> 2;            // A staging: row 0..63
    const int ak  = (t & 3) << 3;      // A staging: k offset 0,8,16,24
    const int bn2 = (t & 63) * 2;      // B staging: col pair base 0..126
    const int bk0 = (t >> 6) * 8;      // B staging: k base 0,8,16,24

    const float*    Ap = A + (size_t)(m0 + am) * K + ak;
    const unsigned* Bp = B + (size_t)bk0 * N + n0 + bn2;

    f32x4 acc[4][2];
#pragma unroll
    for (int mt = 0; mt < 4; mt++)
#pragma unroll
        for (int nt = 0; nt < 2; nt++) acc[mt][nt] = (f32x4){0.f, 0.f, 0.f, 0.f};

    f16x4 pah[2], pal[2];
    f16x8 bh0, bh1, bl0, bl1;

    auto load_convert = [&](int k0) {
        float4 a0 = *(const float4*)(Ap + k0);
        float4 a1 = *(const float4*)(Ap + k0 + 4);
        float av[8] = {a0.x, a0.y, a0.z, a0.w, a1.x, a1.y, a1.z, a1.w};
#pragma unroll
        for (int g = 0; g < 2; g++)
#pragma unroll
            for (int j = 0; j < 4; j++) {
                float x = av[g * 4 + j];
                _Float16 h = (_Float16)x;
                pah[g][j] = h;
                if constexpr (SPLIT == 3) pal[g][j] = (_Float16)(x - (float)h);
            }
#pragma unroll
        for (int i = 0; i < 8; i++) {
            uint2 u = *(const uint2*)(Bp + (size_t)(k0 + i) * N);
            bh0[i] = u2h((unsigned short)(u.x & 0xffffu));
            bh1[i] = u2h((unsigned short)(u.y & 0xffffu));
            if constexpr (SPLIT == 3) {
                bl0[i] = u2h((unsigned short)(u.x >> 16));
                bl1[i] = u2h((unsigned short)(u.y >> 16));
            }
        }
    };

    load_convert(0);

    for (int k0 = 0; k0 < K; k0 += 32) {
        __syncthreads();
#pragma unroll
        for (int g = 0; g < 2; g++) {
            *(f16x4*)&smem[AH + am * 40 + ak + 4 * g] = pah[g];
            if constexpr (SPLIT == 3) *(f16x4*)&smem[AL + am * 40 + ak + 4 * g] = pal[g];
        }
        *(f16x8*)&smem[BH + (bn2    ) * 40 + bk0] = bh0;
        *(f16x8*)&smem[BH + (bn2 + 1) * 40 + bk0] = bh1;
        if constexpr (SPLIT == 3) {
            *(f16x8*)&smem[BL + (bn2    ) * 40 + bk0] = bl0;
            *(f16x8*)&smem[BL + (bn2 + 1) * 40 + bk0] = bl1;
        }
        __syncthreads();

        if (k0 + 32 < K) load_convert(k0 + 32);

        f16x8 a_h[4], a_l[4], b_h[2], b_l[2];
#pragma unroll
        for (int mt = 0; mt < 4; mt++) {
            a_h[mt] = *(f16x8*)&smem[AH + (mt * 16 + col) * 40 + quad * 8];
            if constexpr (SPLIT == 3)
                a_l[mt] = *(f16x8*)&smem[AL + (mt * 16 + col) * 40 + quad * 8];
        }
#pragma unroll
        for (int nt = 0; nt < 2; nt++) {
            b_h[nt] = *(f16x8*)&smem[BH + (wn + nt * 16 + col) * 40 + quad * 8];
            if constexpr (SPLIT == 3)
                b_l[nt] = *(f16x8*)&smem[BL + (wn + nt * 16 + col) * 40 + quad * 8];
        }
#pragma unroll
        for (int nt = 0; nt < 2; nt++)
#pragma unroll
            for (int mt = 0; mt < 4; mt++) {
                acc[mt][nt] = __builtin_amdgcn_mfma_f32_16x16x32_f16(a_h[mt], b_h[nt], acc[mt][nt], 0, 0, 0);
                if constexpr (SPLIT == 3) {
                    acc[mt][nt] = __builtin_amdgcn_mfma_f32_16x16x32_f16(a_h[mt], b_l[nt], acc[mt][nt], 0, 0, 0);
                    acc[mt][nt] = __builtin_amdgcn_mfma_f32_16x16x32_f16(a_l[mt], b_h[nt], acc[mt][nt], 0, 0, 0);
                }
            }
    }

    const float inv = 1.0f / 32.0f;    // undo pack-time x32 B scaling
#pragma unroll
    for (int mt = 0; mt < 4; mt++)
#pragma unroll
        for (int nt = 0; nt < 2; nt++)
#pragma unroll
            for (int r = 0; r < 4; r++) {
                float val = acc[mt][nt][r] * inv;
                size_t idx = (size_t)(m0 + mt * 16 + quad * 4 + r) * N + n0 + wn + nt * 16 + col;
                if constexpr (SPLIT == 3) {
                    _Float16 h = (_Float16)val;
                    _Float16 l = (_Float16)(val - (float)h);
                    C[idx] = (unsigned)h2u(h) | ((unsigned)h2u(l) << 16);
                } else if constexpr (__is_same(CT, _Float16)) {
                    C[idx] = (_Float16)val;
                } else {
                    C[idx] = val;
                }
            }
}

// ---------------------------------------------------------------------------
// MFMA flash attention (causal), XCD-pinned block mapping.
// Softmax on UNSCALED scores (reference quirk), /sqrt(64)=8 at the end.
// l is accumulated via MFMA row-sum: a 5th C-tile P @ ones (B-frag is a
// constant splat(1) -> no LDS read, no shuffle reduction for the sum).
// ---------------------------------------------------------------------------
#define LDS_STRIDE 72
#define KHI_OFF 0
#define KLO_OFF (64 * LDS_STRIDE)
#define VT_OFF  (2 * 64 * LDS_STRIDE)
#define VT_SIZE (64 * LDS_STRIDE + 64)
#define P_OFF   (VT_OFF + VT_SIZE)
#define P_WAVE  (16 * LDS_STRIDE)
#define SMEM_HALVES (P_OFF + 4 * P_WAVE)

__global__ __launch_bounds__(256) void attn_mfma(unsigned* __restrict__ qa,
                                                 const unsigned* __restrict__ kh,
                                                 const _Float16* __restrict__ vh)
{
    __shared__ __align__(16) _Float16 smem[SMEM_HALVES];

    const int i  = blockIdx.x;               // 0..1023
    const int j  = i >> 3;
    const int bh = (i & 7) + ((j & 3) << 3); // pin (b,h) to XCD i&7
    const int qt = (SEQ / 64 - 1) - (j >> 2);
    const int b  = bh >> 4;
    const int h  = bh & 15;
    const int qb = qt * 64;

    const int t    = threadIdx.x;
    const int wave = t >> 6;
    const int lane = t & 63;
    const int quad = lane >> 4;
    const int col  = lane & 15;

    const size_t bbase = (size_t)b * SEQ * DMODEL + (size_t)h * DHEAD;
    const unsigned* kb_ptr = kh + bbase;
    const _Float16* vb_ptr = vh + bbase;

    // --- Q fragments (A-operand, hi/lo) from packed uint32 ---
    const int qm = qb + wave * 16 + col;
    f16x8 qhi[2], qlo[2];
    {
        const unsigned* qp = qa + bbase + (size_t)qm * DMODEL + quad * 8;
#pragma unroll
        for (int kt = 0; kt < 2; kt++) {
            uint4 u0 = *(const uint4*)(qp + kt * 32);
            uint4 u1 = *(const uint4*)(qp + kt * 32 + 4);
            unsigned us[8] = {u0.x, u0.y, u0.z, u0.w, u1.x, u1.y, u1.z, u1.w};
#pragma unroll
            for (int jj = 0; jj < 8; jj++) {
                qhi[kt][jj] = u2h((unsigned short)(us[jj] & 0xffffu));
                qlo[kt][jj] = u2h((unsigned short)(us[jj] >> 16));
            }
        }
    }

    const int srow = t >> 2;           // staging: key row 0..63
    const int sdg  = (t & 3) << 4;     // staging: d-group 0,16,32,48
    const int vswz = (t & 3) * 16;     // VT bank swizzle

    f16x8 kOnes;
#pragma unroll
    for (int jj = 0; jj < 8; jj++) kOnes[jj] = (_Float16)1.0f;

    float m_i[4];
    f32x4 l4;                          // MFMA-accumulated row sums
    f32x4 o[4];
#pragma unroll
    for (int r = 0; r < 4; r++) m_i[r] = -1e30f;
    l4 = (f32x4){0.f, 0.f, 0.f, 0.f};
#pragma unroll
    for (int dt = 0; dt < 4; dt++) o[dt] = (f32x4){0.f, 0.f, 0.f, 0.f};

    const int wq0 = qb + wave * 16;
    _Float16* Pw = &smem[P_OFF + wave * P_WAVE];

    f16x8 pkhi[2], pklo[2], pv[2];
    auto load_tile = [&](int kb) {
        const unsigned* kp = kb_ptr + (size_t)(kb + srow) * DMODEL + sdg;
        uint4 u0 = *(const uint4*)(kp + 0);
        uint4 u1 = *(const uint4*)(kp + 4);
        uint4 u2 = *(const uint4*)(kp + 8);
        uint4 u3 = *(const uint4*)(kp + 12);
        unsigned us[16] = {u0.x, u0.y, u0.z, u0.w, u1.x, u1.y, u1.z, u1.w,
                           u2.x, u2.y, u2.z, u2.w, u3.x, u3.y, u3.z, u3.w};
#pragma unroll
        for (int g = 0; g < 2; g++)
#pragma unroll
            for (int jj = 0; jj < 8; jj++) {
                pkhi[g][jj] = u2h((unsigned short)(us[g * 8 + jj] & 0xffffu));
                pklo[g][jj] = u2h((unsigned short)(us[g * 8 + jj] >> 16));
            }
        const _Float16* vp = vb_ptr + (size_t)(kb + srow) * DMODEL + sdg;
        pv[0] = *(const f16x8*)vp;
        pv[1] = *(const f16x8*)(vp + 8);
    };

    load_tile(0);

    for (int kb = 0; kb <= qb; kb += 64) {
        __syncthreads();

        *(f16x8*)&smem[KHI_OFF + srow * LDS_STRIDE + sdg]     = pkhi[0];
        *(f16x8*)&smem[KHI_OFF + srow * LDS_STRIDE + sdg + 8] = pkhi[1];
        *(f16x8*)&smem[KLO_OFF + srow * LDS_STRIDE + sdg]     = pklo[0];
        *(f16x8*)&smem[KLO_OFF + srow * LDS_STRIDE + sdg + 8] = pklo[1];
#pragma unroll
        for (int jj = 0; jj < 8; jj++) {
            smem[VT_OFF + (sdg + jj    ) * LDS_STRIDE + vswz + srow] = pv[0][jj];
            smem[VT_OFF + (sdg + 8 + jj) * LDS_STRIDE + vswz + srow] = pv[1][jj];
        }
        __syncthreads();

        if (kb + 64 <= qb) load_tile(kb + 64);

        // ---- QK^T: 16q x 64keys, split-f16 (3 MFMAs) ----
        f32x4 acc[4];
#pragma unroll
        for (int ct = 0; ct < 4; ct++) acc[ct] = (f32x4){0.f, 0.f, 0.f, 0.f};
#pragma unroll
        for (int kt = 0; kt < 2; kt++) {
#pragma unroll
            for (int ct = 0; ct < 4; ct++) {
                f16x8 bhi = *(f16x8*)&smem[KHI_OFF + (ct * 16 + col) * LDS_STRIDE + kt * 32 + quad * 8];
                f16x8 blo = *(f16x8*)&smem[KLO_OFF + (ct * 16 + col) * LDS_STRIDE + kt * 32 + quad * 8];
                acc[ct] = __builtin_amdgcn_mfma_f32_16x16x32_f16(qhi[kt], bhi, acc[ct], 0, 0, 0);
                acc[ct] = __builtin_amdgcn_mfma_f32_16x16x32_f16(qhi[kt], blo, acc[ct], 0, 0, 0);
                acc[ct] = __builtin_amdgcn_mfma_f32_16x16x32_f16(qlo[kt], bhi, acc[ct], 0, 0, 0);
            }
        }

        // ---- online softmax (C-layout: row=quad*4+r, col=lane&15+16*ct) ----
        const bool need_mask = (kb + 63 > wq0);
#pragma unroll
        for (int r = 0; r < 4; r++) {
            const int qrow = wq0 + quad * 4 + r;
            float s0 = acc[0][r], s1 = acc[1][r], s2 = acc[2][r], s3 = acc[3][r];
            if (need_mask) {
                s0 = (kb +  0 + col <= qrow) ? s0 : -1e30f;
                s1 = (kb + 16 + col <= qrow) ? s1 : -1e30f;
                s2 = (kb + 32 + col <= qrow) ? s2 : -1e30f;
                s3 = (kb + 48 + col <= qrow) ? s3 : -1e30f;
            }
            float rm = fmaxf(fmaxf(s0, s1), fmaxf(s2, s3));
#pragma unroll
            for (int off = 1; off <= 8; off <<= 1)
                rm = fmaxf(rm, __shfl_xor(rm, off, 64));
            const float mnew  = fmaxf(m_i[r], rm);
            const float alpha = __expf(m_i[r] - mnew);
            const float p0 = __expf(s0 - mnew), p1 = __expf(s1 - mnew);
            const float p2 = __expf(s2 - mnew), p3 = __expf(s3 - mnew);
            m_i[r] = mnew;
            l4[r] *= alpha;
#pragma unroll
            for (int dt = 0; dt < 4; dt++) o[dt][r] *= alpha;
            const int prow = quad * 4 + r;
            Pw[prow * LDS_STRIDE + col     ] = (_Float16)p0;
            Pw[prow * LDS_STRIDE + col + 16] = (_Float16)p1;
            Pw[prow * LDS_STRIDE + col + 32] = (_Float16)p2;
            Pw[prow * LDS_STRIDE + col + 48] = (_Float16)p3;
        }

        // ---- PV: O += P(16x64) @ V(64x64); l += P @ ones (row-sum tile) ----
#pragma unroll
        for (int kt = 0; kt < 2; kt++) {
            f16x8 a = *(f16x8*)&Pw[col * LDS_STRIDE + kt * 32 + quad * 8];
            l4 = __builtin_amdgcn_mfma_f32_16x16x32_f16(a, kOnes, l4, 0, 0, 0);
#pragma unroll
            for (int dt = 0; dt < 4; dt++) {
                f16x8 bv = *(f16x8*)&smem[VT_OFF + (dt * 16 + col) * LDS_STRIDE + (dt & 3) * 16 + kt * 32 + quad * 8];
                o[dt] = __builtin_amdgcn_mfma_f32_16x16x32_f16(a, bv, o[dt], 0, 0, 0);
            }
        }
    }

    // ---- epilogue: /l, /8; write att (fp32 bits) over packed qh ----
#pragma unroll
    for (int r = 0; r < 4; r++) {
        const float inv = 1.0f / (l4[r] * 8.0f);
        const int q = wq0 + quad * 4 + r;
        unsigned* op = qa + bbase + (size_t)q * DMODEL;
#pragma unroll
        for (int dt = 0; dt < 4; dt++)
            op[dt * 16 + col] = __float_as_uint(o[dt][r] * inv);
    }
}

// ---------------------------------------------------------------------------
// Launch. Inputs: q, k, v, mask(ignored), Wq, Wk, Wv, Wo — all fp32.
// Scratch choreography (ws >= 32 MB; d_out = 16 MB rotating scratch):
//   1. pack Wq->d_out[0,4), Wk->[4,8), Wv->[8,12)   (one launch)
//   2. gemm QK (one launch, z=2): q@WqP->qh ws[0,16), k@WkP->kh ws[16,32)
//   3. gemm V: v@WvP -> vh f16 = d_out[0,8)         [WqP,WkP dead]
//   4. attn(qh,kh,vh) -> att fp32 over qh           [vh,WvP dead]
//   5. pack Wo -> kh region (dead after attn)
//   6. gemm O: att@WoP -> out = d_out[0,16)
// ---------------------------------------------------------------------------
extern "C" void kernel_launch(void* const* d_in, const int* in_sizes, int n_in,
                              void* d_out, int out_size, void* d_ws, size_t ws_size,
                              hipStream_t stream)
{
    const float* q  = (const float*)d_in[0];
    const float* k  = (const float*)d_in[1];
    const float* v  = (const float*)d_in[2];
    const float* Wq = (const float*)d_in[4];
    const float* Wk = (const float*)d_in[5];
    const float* Wv = (const float*)d_in[6];
    const float* Wo = (const float*)d_in[7];
    float* out = (float*)d_out;

    const int    M   = BATCH * SEQ;            // 4096
    const size_t npe = (size_t)M * DMODEL;     // 4,194,304
    const size_t nw  = (size_t)DMODEL * DMODEL;// 1,048,576

    unsigned* qh  = (unsigned*)d_ws;                 // ws[0,16)
    unsigned* kh  = qh + npe;                        // ws[16,32)
    unsigned* WqP = (unsigned*)d_out;                // d_out[0,4)
    unsigned* WkP = WqP + nw;                        // d_out[4,8)
    unsigned* WvP = WkP + nw;                        // d_out[8,12)
    _Float16* vh  = (_Float16*)d_out;                // d_out[0,8) after QK
    unsigned* WoP = kh;                              // kh region after attn

    dim3 b256(256);
    dim3 pgrid(DMODEL * DMODEL / 1024, 3);     // pack: 4 elems/thread
    dim3 pgrid1(DMODEL * DMODEL / 1024);
    dim3 gqk(M / 64, DMODEL / 128, 2);         // (64, 8, 2) = 1024 blocks
    dim3 g1(M / 64, DMODEL / 128, 1);          // (64, 8)
    dim3 agrid(1024);                          // XCD-pinned 1D

    pack_w3<<<pgrid, b256, 0, stream>>>(Wq, Wk, Wv, WqP, WkP, WvP);
    gemm_mfma<3, unsigned><<<gqk, b256, 0, stream>>>(q, k, WqP, WkP, qh, kh, DMODEL, DMODEL);
    gemm_mfma<1, _Float16><<<g1, b256, 0, stream>>>(v, v, WvP, WvP, vh, vh, DMODEL, DMODEL);
    attn_mfma<<<agrid, b256, 0, stream>>>(qh, kh, vh);
    pack_w1<<<pgrid1, b256, 0, stream>>>(Wo, WoP);
    gemm_mfma<1, float><<<g1, b256, 0, stream>>>((const float*)qh, (const float*)qh, WoP, WoP, out, out, DMODEL, DMODEL);
}

// Round 8
// 352.469 us; speedup vs baseline: 12.5533x; 1.0190x over previous
//
#include <hip/hip_runtime.h>
#include <hip/hip_bf16.h>

// Problem constants (fixed by the reference)
#define BATCH  2
#define SEQ    2048
#define DMODEL 1024
#define NHEAD  16
#define DHEAD  64

typedef _Float16 f16x4 __attribute__((ext_vector_type(4)));
typedef _Float16 f16x8 __attribute__((ext_vector_type(8)));
typedef float    f32x4 __attribute__((ext_vector_type(4)));

union H16 { unsigned short u; _Float16 f; };
__device__ __forceinline__ _Float16 u2h(unsigned short u) { H16 c; c.u = u; return c.f; }
__device__ __forceinline__ unsigned short h2u(_Float16 f) { H16 c; c.f = f; return c.u; }

// async global->LDS, 16 B per lane; LDS dest must be wave-uniform base
// (HW writes base + lane*16), global ptr is per-lane.
__device__ __forceinline__ void gll16(const void* g, void* l) {
    __builtin_amdgcn_global_load_lds(
        (const __attribute__((address_space(1))) void*)g,
        (__attribute__((address_space(3))) void*)l, 16, 0, 0);
}

// ---------------------------------------------------------------------------
// Weight pack: W[k][n] fp32 -> WT[n][k] f16 hi (and lo) planes, x32 scaled
// (W ~ N(0,1/32): keeps lo residuals normal; GEMM epilogue undoes).
// Within each 64-B k-group of a row, logical chunk c (8 halves) is stored at
// physical slot c ^ sw(n), sw(n) = (n&3)^((n>>2)&3): makes the unpadded
// stride-32 LDS frag reads 2-way (free) instead of 8-way conflicted.
// ---------------------------------------------------------------------------
__device__ __forceinline__ void pack_body(const float* __restrict__ W,
                                          _Float16* __restrict__ Phi,
                                          _Float16* __restrict__ Plo)
{
    const int n0 = blockIdx.x * 64;
    const int k0 = blockIdx.y * 64;
    const int t  = threadIdx.x;
    const int nl = t & 63;
    const int kc = (t >> 6) * 16;          // 0,16,32,48
    const int n  = n0 + nl;
    const int sw = (n & 3) ^ ((n >> 2) & 3);

    _Float16 hi[16], lo[16];
#pragma unroll
    for (int i = 0; i < 16; i++) {
        float x = W[(size_t)(k0 + kc + i) * DMODEL + n] * 32.0f;
        _Float16 h = (_Float16)x;
        hi[i] = h;
        lo[i] = (_Float16)(x - (float)h);
    }
#pragma unroll
    for (int cc = 0; cc < 2; cc++) {
        const int kk = kc + cc * 8;        // half-offset within this 64-k tile
        const int g  = kk >> 5;            // 64-B group index
        const int c  = (kk >> 3) & 3;      // logical chunk in group
        const size_t off = (size_t)n * DMODEL + k0 + g * 32 + ((c ^ sw) << 3);
        *(f16x8*)&Phi[off] = *(f16x8*)&hi[cc * 8];
        if (Plo) *(f16x8*)&Plo[off] = *(f16x8*)&lo[cc * 8];
    }
}

__global__ __launch_bounds__(256) void pack_qkv(const float* __restrict__ Wq,
                                                const float* __restrict__ Wk,
                                                const float* __restrict__ Wv,
                                                _Float16* qhiT, _Float16* qloT,
                                                _Float16* khiT, _Float16* kloT,
                                                _Float16* vhiT)
{
    const int z = blockIdx.z;
    pack_body(z == 0 ? Wq : z == 1 ? Wk : Wv,
              z == 0 ? qhiT : z == 1 ? khiT : vhiT,
              z == 0 ? qloT : z == 1 ? kloT : nullptr);
}

__global__ __launch_bounds__(256) void pack_one(const float* __restrict__ W,
                                                _Float16* Phi)
{
    pack_body(W, Phi, nullptr);
}

// ---------------------------------------------------------------------------
// m97-style MFMA GEMM: C[M,N] = A[M,K] @ B[K,N]; A fp32 (in-kernel hi/lo
// convert, padded LDS stride 40), B from pre-packed TRANSPOSED hi/lo planes
// staged via global_load_lds (16 B, double-buffered, chunk-swizzled).
// 128x128 block tile, 4 waves x (64x64), BK=32, 16x16x32 MFMA.
// SPLIT=3: Markidis fp32-grade (AhiBhi+AhiBlo+AloBhi). SPLIT=1: hi only.
// blockIdx.z picks (A,B,C) triple -> Q and K projections in ONE launch.
// ---------------------------------------------------------------------------
template <int SPLIT, typename CT>
__global__ __launch_bounds__(256) void gemm_mfma(const float* __restrict__ A0,
                                                 const float* __restrict__ A1,
                                                 const _Float16* __restrict__ Bh0,
                                                 const _Float16* __restrict__ Bl0,
                                                 const _Float16* __restrict__ Bh1,
                                                 const _Float16* __restrict__ Bl1,
                                                 CT* __restrict__ C0,
                                                 CT* __restrict__ C1,
                                                 int N, int K)
{
    constexpr int ASZ = 128 * 40;          // padded A plane (halves)
    constexpr int BSZ = 128 * 32;          // unpadded B plane buffer (halves)
    constexpr int AHI = 0;
    constexpr int ALO = ASZ;                       // SPLIT3 only
    constexpr int BHI = ASZ * (SPLIT == 3 ? 2 : 1);
    constexpr int BLO = BHI + 2 * BSZ;             // SPLIT3 only
    constexpr int TOT = BHI + 2 * BSZ * (SPLIT == 3 ? 2 : 1);
    __shared__ __align__(16) _Float16 smem[TOT];

    const float*    A  = blockIdx.z ? A1 : A0;
    const _Float16* Bh = blockIdx.z ? Bh1 : Bh0;
    const _Float16* Bl = blockIdx.z ? Bl1 : Bl0;
    CT*             C  = blockIdx.z ? C1 : C0;

    const int m0 = blockIdx.x * 128;
    const int n0 = blockIdx.y * 128;
    const int t    = threadIdx.x;
    const int wave = t >> 6;
    const int lane = t & 63;
    const int quad = lane >> 4;
    const int col  = lane & 15;
    const int wm   = (wave & 1) * 64;
    const int wn   = (wave >> 1) * 64;

    // A staging: thread covers row t>>1, k-halves (t&1)*16..+15
    const int ar  = t >> 1;
    const int akc = (t & 1) * 16;
    const float* Ap = A + (size_t)(m0 + ar) * K + akc;

    // B gll: wave w stages plane rows w*32..w*32+31 (2 instrs of 16 rows)
    const _Float16* BhSrc = Bh + (size_t)(n0 + wave * 32 + (lane >> 2)) * K + (lane & 3) * 8;
    const _Float16* BlSrc = (SPLIT == 3)
        ? Bl + (size_t)(n0 + wave * 32 + (lane >> 2)) * K + (lane & 3) * 8 : nullptr;

    // frag-read swizzle (must match pack_body's sw(n))
    const int qe8 = (quad ^ ((col & 3) ^ ((col >> 2) & 3))) * 8;

    f32x4 acc[4][4];
#pragma unroll
    for (int mt = 0; mt < 4; mt++)
#pragma unroll
        for (int nt = 0; nt < 4; nt++) acc[mt][nt] = (f32x4){0.f, 0.f, 0.f, 0.f};

    float av[16];
    auto loadA = [&](int k0) {
#pragma unroll
        for (int g = 0; g < 4; g++) {
            float4 x = *(const float4*)(Ap + k0 + g * 4);
            av[g * 4 + 0] = x.x; av[g * 4 + 1] = x.y;
            av[g * 4 + 2] = x.z; av[g * 4 + 3] = x.w;
        }
    };
    auto issueB = [&](int k0, int buf) {
        _Float16* d0 = &smem[BHI + buf * BSZ + wave * 1024];
        gll16(BhSrc + k0, d0);
        gll16(BhSrc + (size_t)16 * K + k0, d0 + 512);
        if constexpr (SPLIT == 3) {
            _Float16* d1 = &smem[BLO + buf * BSZ + wave * 1024];
            gll16(BlSrc + k0, d1);
            gll16(BlSrc + (size_t)16 * K + k0, d1 + 512);
        }
    };
    auto storeA = [&]() {
#pragma unroll
        for (int g = 0; g < 2; g++) {
            f16x8 h, l;
#pragma unroll
            for (int j = 0; j < 8; j++) {
                float x = av[g * 8 + j];
                _Float16 hh = (_Float16)x;
                h[j] = hh;
                l[j] = (_Float16)(x - (float)hh);
            }
            *(f16x8*)&smem[AHI + ar * 40 + akc + g * 8] = h;
            if constexpr (SPLIT == 3)
                *(f16x8*)&smem[ALO + ar * 40 + akc + g * 8] = l;
        }
    };

    loadA(0);
    issueB(0, 0);

    int buf = 0;
    for (int k0 = 0; k0 < K; k0 += 32, buf ^= 1) {
        storeA();
        __syncthreads();               // A stores visible; B(buf) gll landed

        if (k0 + 32 < K) { issueB(k0 + 32, buf ^ 1); loadA(k0 + 32); }

        f16x8 ah[4], al[4], bh[4], bl[4];
#pragma unroll
        for (int mt = 0; mt < 4; mt++) {
            ah[mt] = *(f16x8*)&smem[AHI + (wm + mt * 16 + col) * 40 + quad * 8];
            if constexpr (SPLIT == 3)
                al[mt] = *(f16x8*)&smem[ALO + (wm + mt * 16 + col) * 40 + quad * 8];
        }
#pragma unroll
        for (int nt = 0; nt < 4; nt++) {
            bh[nt] = *(f16x8*)&smem[BHI + buf * BSZ + (wn + nt * 16 + col) * 32 + qe8];
            if constexpr (SPLIT == 3)
                bl[nt] = *(f16x8*)&smem[BLO + buf * BSZ + (wn + nt * 16 + col) * 32 + qe8];
        }
#pragma unroll
        for (int nt = 0; nt < 4; nt++)
#pragma unroll
            for (int mt = 0; mt < 4; mt++) {
                acc[mt][nt] = __builtin_amdgcn_mfma_f32_16x16x32_f16(ah[mt], bh[nt], acc[mt][nt], 0, 0, 0);
                if constexpr (SPLIT == 3) {
                    acc[mt][nt] = __builtin_amdgcn_mfma_f32_16x16x32_f16(ah[mt], bl[nt], acc[mt][nt], 0, 0, 0);
                    acc[mt][nt] = __builtin_amdgcn_mfma_f32_16x16x32_f16(al[mt], bh[nt], acc[mt][nt], 0, 0, 0);
                }
            }
        __syncthreads();               // frag reads done before next A store
    }

    const float inv = 1.0f / 32.0f;    // undo pack-time x32 B scaling
#pragma unroll
    for (int mt = 0; mt < 4; mt++)
#pragma unroll
        for (int nt = 0; nt < 4; nt++)
#pragma unroll
            for (int r = 0; r < 4; r++) {
                float val = acc[mt][nt][r] * inv;
                size_t idx = (size_t)(m0 + wm + mt * 16 + quad * 4 + r) * N
                           + n0 + wn + nt * 16 + col;
                if constexpr (SPLIT == 3) {
                    _Float16 h = (_Float16)val;
                    _Float16 l = (_Float16)(val - (float)h);
                    C[idx] = (unsigned)h2u(h) | ((unsigned)h2u(l) << 16);
                } else if constexpr (__is_same(CT, _Float16)) {
                    C[idx] = (_Float16)val;
                } else {
                    C[idx] = val;
                }
            }
}

// ---------------------------------------------------------------------------
// MFMA flash attention (causal), XCD-pinned block mapping. Unchanged from the
// passing round except the fully-masked-tile early-skip is restored.
// Softmax on UNSCALED scores (reference quirk), /sqrt(64)=8 at the end.
// l via MFMA row-sum (P @ splat(1)).
// ---------------------------------------------------------------------------
#define LDS_STRIDE 72
#define KHI_OFF 0
#define KLO_OFF (64 * LDS_STRIDE)
#define VT_OFF  (2 * 64 * LDS_STRIDE)
#define VT_SIZE (64 * LDS_STRIDE + 64)
#define P_OFF   (VT_OFF + VT_SIZE)
#define P_WAVE  (16 * LDS_STRIDE)
#define SMEM_HALVES (P_OFF + 4 * P_WAVE)

__global__ __launch_bounds__(256) void attn_mfma(unsigned* __restrict__ qa,
                                                 const unsigned* __restrict__ kh,
                                                 const _Float16* __restrict__ vh)
{
    __shared__ __align__(16) _Float16 smem[SMEM_HALVES];

    const int i  = blockIdx.x;               // 0..1023
    const int j  = i >> 3;
    const int bh = (i & 7) + ((j & 3) << 3); // pin (b,h) to XCD i&7
    const int qt = (SEQ / 64 - 1) - (j >> 2);
    const int b  = bh >> 4;
    const int h  = bh & 15;
    const int qb = qt * 64;

    const int t    = threadIdx.x;
    const int wave = t >> 6;
    const int lane = t & 63;
    const int quad = lane >> 4;
    const int col  = lane & 15;

    const size_t bbase = (size_t)b * SEQ * DMODEL + (size_t)h * DHEAD;
    const unsigned* kb_ptr = kh + bbase;
    const _Float16* vb_ptr = vh + bbase;

    const int qm = qb + wave * 16 + col;
    f16x8 qhi[2], qlo[2];
    {
        const unsigned* qp = qa + bbase + (size_t)qm * DMODEL + quad * 8;
#pragma unroll
        for (int kt = 0; kt < 2; kt++) {
            uint4 u0 = *(const uint4*)(qp + kt * 32);
            uint4 u1 = *(const uint4*)(qp + kt * 32 + 4);
            unsigned us[8] = {u0.x, u0.y, u0.z, u0.w, u1.x, u1.y, u1.z, u1.w};
#pragma unroll
            for (int jj = 0; jj < 8; jj++) {
                qhi[kt][jj] = u2h((unsigned short)(us[jj] & 0xffffu));
                qlo[kt][jj] = u2h((unsigned short)(us[jj] >> 16));
            }
        }
    }

    const int srow = t >> 2;
    const int sdg  = (t & 3) << 4;
    const int vswz = (t & 3) * 16;

    f16x8 kOnes;
#pragma unroll
    for (int jj = 0; jj < 8; jj++) kOnes[jj] = (_Float16)1.0f;

    float m_i[4];
    f32x4 l4 = (f32x4){0.f, 0.f, 0.f, 0.f};
    f32x4 o[4];
#pragma unroll
    for (int r = 0; r < 4; r++) m_i[r] = -1e30f;
#pragma unroll
    for (int dt = 0; dt < 4; dt++) o[dt] = (f32x4){0.f, 0.f, 0.f, 0.f};

    const int wq0 = qb + wave * 16;
    _Float16* Pw = &smem[P_OFF + wave * P_WAVE];

    f16x8 pkhi[2], pklo[2], pv[2];
    auto load_tile = [&](int kb) {
        const unsigned* kp = kb_ptr + (size_t)(kb + srow) * DMODEL + sdg;
        uint4 u0 = *(const uint4*)(kp + 0);
        uint4 u1 = *(const uint4*)(kp + 4);
        uint4 u2 = *(const uint4*)(kp + 8);
        uint4 u3 = *(const uint4*)(kp + 12);
        unsigned us[16] = {u0.x, u0.y, u0.z, u0.w, u1.x, u1.y, u1.z, u1.w,
                           u2.x, u2.y, u2.z, u2.w, u3.x, u3.y, u3.z, u3.w};
#pragma unroll
        for (int g = 0; g < 2; g++)
#pragma unroll
            for (int jj = 0; jj < 8; jj++) {
                pkhi[g][jj] = u2h((unsigned short)(us[g * 8 + jj] & 0xffffu));
                pklo[g][jj] = u2h((unsigned short)(us[g * 8 + jj] >> 16));
            }
        const _Float16* vp = vb_ptr + (size_t)(kb + srow) * DMODEL + sdg;
        pv[0] = *(const f16x8*)vp;
        pv[1] = *(const f16x8*)(vp + 8);
    };

    load_tile(0);

    for (int kb = 0; kb <= qb; kb += 64) {
        __syncthreads();

        *(f16x8*)&smem[KHI_OFF + srow * LDS_STRIDE + sdg]     = pkhi[0];
        *(f16x8*)&smem[KHI_OFF + srow * LDS_STRIDE + sdg + 8] = pkhi[1];
        *(f16x8*)&smem[KLO_OFF + srow * LDS_STRIDE + sdg]     = pklo[0];
        *(f16x8*)&smem[KLO_OFF + srow * LDS_STRIDE + sdg + 8] = pklo[1];
#pragma unroll
        for (int jj = 0; jj < 8; jj++) {
            smem[VT_OFF + (sdg + jj    ) * LDS_STRIDE + vswz + srow] = pv[0][jj];
            smem[VT_OFF + (sdg + 8 + jj) * LDS_STRIDE + vswz + srow] = pv[1][jj];
        }
        __syncthreads();

        if (kb + 64 <= qb) load_tile(kb + 64);

        if (kb > wq0 + 15) continue;   // fully masked for this wave (uniform)

        f32x4 acc[4];
#pragma unroll
        for (int ct = 0; ct < 4; ct++) acc[ct] = (f32x4){0.f, 0.f, 0.f, 0.f};
#pragma unroll
        for (int kt = 0; kt < 2; kt++) {
#pragma unroll
            for (int ct = 0; ct < 4; ct++) {
                f16x8 bhi = *(f16x8*)&smem[KHI_OFF + (ct * 16 + col) * LDS_STRIDE + kt * 32 + quad * 8];
                f16x8 blo = *(f16x8*)&smem[KLO_OFF + (ct * 16 + col) * LDS_STRIDE + kt * 32 + quad * 8];
                acc[ct] = __builtin_amdgcn_mfma_f32_16x16x32_f16(qhi[kt], bhi, acc[ct], 0, 0, 0);
                acc[ct] = __builtin_amdgcn_mfma_f32_16x16x32_f16(qhi[kt], blo, acc[ct], 0, 0, 0);
                acc[ct] = __builtin_amdgcn_mfma_f32_16x16x32_f16(qlo[kt], bhi, acc[ct], 0, 0, 0);
            }
        }

        const bool need_mask = (kb + 63 > wq0);
#pragma unroll
        for (int r = 0; r < 4; r++) {
            const int qrow = wq0 + quad * 4 + r;
            float s0 = acc[0][r], s1 = acc[1][r], s2 = acc[2][r], s3 = acc[3][r];
            if (need_mask) {
                s0 = (kb +  0 + col <= qrow) ? s0 : -1e30f;
                s1 = (kb + 16 + col <= qrow) ? s1 : -1e30f;
                s2 = (kb + 32 + col <= qrow) ? s2 : -1e30f;
                s3 = (kb + 48 + col <= qrow) ? s3 : -1e30f;
            }
            float rm = fmaxf(fmaxf(s0, s1), fmaxf(s2, s3));
#pragma unroll
            for (int off = 1; off <= 8; off <<= 1)
                rm = fmaxf(rm, __shfl_xor(rm, off, 64));
            const float mnew  = fmaxf(m_i[r], rm);
            const float alpha = __expf(m_i[r] - mnew);
            const float p0 = __expf(s0 - mnew), p1 = __expf(s1 - mnew);
            const float p2 = __expf(s2 - mnew), p3 = __expf(s3 - mnew);
            m_i[r] = mnew;
            l4[r] *= alpha;
#pragma unroll
            for (int dt = 0; dt < 4; dt++) o[dt][r] *= alpha;
            const int prow = quad * 4 + r;
            Pw[prow * LDS_STRIDE + col     ] = (_Float16)p0;
            Pw[prow * LDS_STRIDE + col + 16] = (_Float16)p1;
            Pw[prow * LDS_STRIDE + col + 32] = (_Float16)p2;
            Pw[prow * LDS_STRIDE + col + 48] = (_Float16)p3;
        }

#pragma unroll
        for (int kt = 0; kt < 2; kt++) {
            f16x8 a = *(f16x8*)&Pw[col * LDS_STRIDE + kt * 32 + quad * 8];
            l4 = __builtin_amdgcn_mfma_f32_16x16x32_f16(a, kOnes, l4, 0, 0, 0);
#pragma unroll
            for (int dt = 0; dt < 4; dt++) {
                f16x8 bv = *(f16x8*)&smem[VT_OFF + (dt * 16 + col) * LDS_STRIDE + (dt & 3) * 16 + kt * 32 + quad * 8];
                o[dt] = __builtin_amdgcn_mfma_f32_16x16x32_f16(a, bv, o[dt], 0, 0, 0);
            }
        }
    }

#pragma unroll
    for (int r = 0; r < 4; r++) {
        const float inv = 1.0f / (l4[r] * 8.0f);
        const int q = wq0 + quad * 4 + r;
        unsigned* op = qa + bbase + (size_t)q * DMODEL;
#pragma unroll
        for (int dt = 0; dt < 4; dt++)
            op[dt * 16 + col] = __float_as_uint(o[dt][r] * inv);
    }
}

// ---------------------------------------------------------------------------
// Launch. Inputs: q, k, v, mask(ignored), Wq, Wk, Wv, Wo — all fp32.
// d_out (16 MB) as rotating scratch, halves-indexed (1M halves = 2 MB):
//   1. pack_qkv: qhiT[0,1M) qloT[1M,2M) khiT[2M,3M) kloT[3M,4M) vhiT[4M,5M)
//   2. gemm QK (z=2): q->qh ws[0,16MB), k->kh ws[16,32)   [q-planes dead]
//   3. gemm V: v @ vhiT -> vh f16 = d_out[0,8MB)          (disjoint from vhiT)
//   4. attn(qh,kh,vh) -> att fp32 over qh                 [vh dead]
//   5. pack_one Wo -> wohiT = kh region (dead)
//   6. gemm O: att @ wohiT -> out = d_out[0,16)
// ---------------------------------------------------------------------------
extern "C" void kernel_launch(void* const* d_in, const int* in_sizes, int n_in,
                              void* d_out, int out_size, void* d_ws, size_t ws_size,
                              hipStream_t stream)
{
    const float* q  = (const float*)d_in[0];
    const float* k  = (const float*)d_in[1];
    const float* v  = (const float*)d_in[2];
    const float* Wq = (const float*)d_in[4];
    const float* Wk = (const float*)d_in[5];
    const float* Wv = (const float*)d_in[6];
    const float* Wo = (const float*)d_in[7];
    float* out = (float*)d_out;

    const int    M   = BATCH * SEQ;             // 4096
    const size_t npe = (size_t)M * DMODEL;      // 4,194,304
    const size_t PW  = (size_t)DMODEL * DMODEL; // 1M halves per plane

    unsigned* qh = (unsigned*)d_ws;             // ws[0,16 MB)
    unsigned* kh = qh + npe;                    // ws[16,32 MB)

    _Float16* dh    = (_Float16*)d_out;
    _Float16* qhiT  = dh;
    _Float16* qloT  = dh + PW;
    _Float16* khiT  = dh + 2 * PW;
    _Float16* kloT  = dh + 3 * PW;
    _Float16* vhiT  = dh + 4 * PW;
    _Float16* vh    = dh;                       // d_out[0,8 MB) after QK gemm
    _Float16* wohiT = (_Float16*)kh;            // kh region after attn

    dim3 b256(256);
    dim3 pk(DMODEL / 64, DMODEL / 64, 3);       // (16,16,3)
    dim3 pk1(DMODEL / 64, DMODEL / 64, 1);
    dim3 gqk(M / 128, DMODEL / 128, 2);         // (32,8,2) = 512 blocks
    dim3 g1(M / 128, DMODEL / 128, 1);          // (32,8)
    dim3 agrid(1024);

    pack_qkv<<<pk, b256, 0, stream>>>(Wq, Wk, Wv, qhiT, qloT, khiT, kloT, vhiT);
    gemm_mfma<3, unsigned><<<gqk, b256, 0, stream>>>(q, k, qhiT, qloT, khiT, kloT,
                                                     qh, kh, DMODEL, DMODEL);
    gemm_mfma<1, _Float16><<<g1, b256, 0, stream>>>(v, v, vhiT, nullptr, vhiT, nullptr,
                                                    vh, vh, DMODEL, DMODEL);
    attn_mfma<<<agrid, b256, 0, stream>>>(qh, kh, vh);
    pack_one<<<pk1, b256, 0, stream>>>(Wo, wohiT);
    gemm_mfma<1, float><<<g1, b256, 0, stream>>>((const float*)qh, (const float*)qh,
                                                 wohiT, nullptr, wohiT, nullptr,
                                                 out, out, DMODEL, DMODEL);
}

// Round 9
// 334.332 us; speedup vs baseline: 13.2343x; 1.0543x over previous
//
#include <hip/hip_runtime.h>
#include <hip/hip_bf16.h>

// Problem constants (fixed by the reference)
#define BATCH  2
#define SEQ    2048
#define DMODEL 1024
#define NHEAD  16
#define DHEAD  64

typedef _Float16 f16x4 __attribute__((ext_vector_type(4)));
typedef _Float16 f16x8 __attribute__((ext_vector_type(8)));
typedef float    f32x4 __attribute__((ext_vector_type(4)));

union H16 { unsigned short u; _Float16 f; };
__device__ __forceinline__ _Float16 u2h(unsigned short u) { H16 c; c.u = u; return c.f; }
__device__ __forceinline__ unsigned short h2u(_Float16 f) { H16 c; c.f = f; return c.u; }

// async global->LDS, 16 B per lane; LDS dest = wave-uniform base + lane*16.
__device__ __forceinline__ void gll16(const void* g, void* l) {
    __builtin_amdgcn_global_load_lds(
        (const __attribute__((address_space(1))) void*)g,
        (__attribute__((address_space(3))) void*)l, 16, 0, 0);
}

// max over the 16 lanes of a DPP row (C-matrix row group), in-register.
__device__ __forceinline__ float dpp_max16(float x) {
    float t;
    t = __int_as_float(__builtin_amdgcn_update_dpp(0, __float_as_int(x), 0xB1, 0xF, 0xF, true));   // quad_perm xor1
    x = fmaxf(x, t);
    t = __int_as_float(__builtin_amdgcn_update_dpp(0, __float_as_int(x), 0x4E, 0xF, 0xF, true));   // quad_perm xor2
    x = fmaxf(x, t);
    t = __int_as_float(__builtin_amdgcn_update_dpp(0, __float_as_int(x), 0x124, 0xF, 0xF, true));  // row_ror:4
    x = fmaxf(x, t);
    t = __int_as_float(__builtin_amdgcn_update_dpp(0, __float_as_int(x), 0x128, 0xF, 0xF, true));  // row_ror:8
    x = fmaxf(x, t);
    return x;
}

// ---------------------------------------------------------------------------
// Weight pack: W[k][n] fp32 -> WT[n][k] f16 hi (and lo) planes, x32 scaled.
// Chunk c (8 halves) within each 64-B group stored at c ^ sw(n),
// sw(n) = (n&3)^((n>>2)&3) — matches the gemm's frag-read swizzle.
// ---------------------------------------------------------------------------
__device__ __forceinline__ void pack_body(const float* __restrict__ W,
                                          _Float16* __restrict__ Phi,
                                          _Float16* __restrict__ Plo)
{
    const int n0 = blockIdx.x * 64;
    const int k0 = blockIdx.y * 64;
    const int t  = threadIdx.x;
    const int nl = t & 63;
    const int kc = (t >> 6) * 16;
    const int n  = n0 + nl;
    const int sw = (n & 3) ^ ((n >> 2) & 3);

    _Float16 hi[16], lo[16];
#pragma unroll
    for (int i = 0; i < 16; i++) {
        float x = W[(size_t)(k0 + kc + i) * DMODEL + n] * 32.0f;
        _Float16 h = (_Float16)x;
        hi[i] = h;
        lo[i] = (_Float16)(x - (float)h);
    }
#pragma unroll
    for (int cc = 0; cc < 2; cc++) {
        const int kk = kc + cc * 8;
        const int g  = kk >> 5;
        const int c  = (kk >> 3) & 3;
        const size_t off = (size_t)n * DMODEL + k0 + g * 32 + ((c ^ sw) << 3);
        *(f16x8*)&Phi[off] = *(f16x8*)&hi[cc * 8];
        if (Plo) *(f16x8*)&Plo[off] = *(f16x8*)&lo[cc * 8];
    }
}

__global__ __launch_bounds__(256) void pack_qkv(const float* __restrict__ Wq,
                                                const float* __restrict__ Wk,
                                                const float* __restrict__ Wv,
                                                _Float16* qhiT, _Float16* qloT,
                                                _Float16* khiT, _Float16* kloT,
                                                _Float16* vhiT)
{
    const int z = blockIdx.z;
    pack_body(z == 0 ? Wq : z == 1 ? Wk : Wv,
              z == 0 ? qhiT : z == 1 ? khiT : vhiT,
              z == 0 ? qloT : z == 1 ? kloT : nullptr);
}

__global__ __launch_bounds__(256) void pack_one(const float* __restrict__ W,
                                                _Float16* Phi)
{
    pack_body(W, Phi, nullptr);
}

// ---------------------------------------------------------------------------
// m97-style MFMA GEMM: C[M,N] = A[M,K] @ B[K,N]; A fp32 (in-kernel hi/lo
// convert), B from pre-packed transposed hi/lo planes via global_load_lds.
// 128x128 tile, 4 waves x (64x64), BK=32. SPLIT=3: Markidis fp32-grade.
// blockIdx.z picks (A,B,C): z=0 -> packed u32 C (Q path); z=1 -> separate
// hi/lo f16 K planes (so attention can gll-stage K directly).
// ---------------------------------------------------------------------------
template <int SPLIT, typename CT>
__global__ __launch_bounds__(256) void gemm_mfma(const float* __restrict__ A0,
                                                 const float* __restrict__ A1,
                                                 const _Float16* __restrict__ Bh0,
                                                 const _Float16* __restrict__ Bl0,
                                                 const _Float16* __restrict__ Bh1,
                                                 const _Float16* __restrict__ Bl1,
                                                 CT* __restrict__ C0,
                                                 CT* __restrict__ C1,
                                                 _Float16* __restrict__ Kh,
                                                 _Float16* __restrict__ Kl,
                                                 int N, int K)
{
    constexpr int ASZ = 128 * 40;
    constexpr int BSZ = 128 * 32;
    constexpr int AHI = 0;
    constexpr int ALO = ASZ;
    constexpr int BHI = ASZ * (SPLIT == 3 ? 2 : 1);
    constexpr int BLO = BHI + 2 * BSZ;
    constexpr int TOT = BHI + 2 * BSZ * (SPLIT == 3 ? 2 : 1);
    __shared__ __align__(16) _Float16 smem[TOT];

    const float*    A  = blockIdx.z ? A1 : A0;
    const _Float16* Bh = blockIdx.z ? Bh1 : Bh0;
    const _Float16* Bl = blockIdx.z ? Bl1 : Bl0;
    CT*             C  = blockIdx.z ? C1 : C0;

    const int m0 = blockIdx.x * 128;
    const int n0 = blockIdx.y * 128;
    const int t    = threadIdx.x;
    const int wave = t >> 6;
    const int lane = t & 63;
    const int quad = lane >> 4;
    const int col  = lane & 15;
    const int wm   = (wave & 1) * 64;
    const int wn   = (wave >> 1) * 64;

    const int ar  = t >> 1;
    const int akc = (t & 1) * 16;
    const float* Ap = A + (size_t)(m0 + ar) * K + akc;

    const _Float16* BhSrc = Bh + (size_t)(n0 + wave * 32 + (lane >> 2)) * K + (lane & 3) * 8;
    const _Float16* BlSrc = (SPLIT == 3)
        ? Bl + (size_t)(n0 + wave * 32 + (lane >> 2)) * K + (lane & 3) * 8 : nullptr;

    const int qe8 = (quad ^ ((col & 3) ^ ((col >> 2) & 3))) * 8;

    f32x4 acc[4][4];
#pragma unroll
    for (int mt = 0; mt < 4; mt++)
#pragma unroll
        for (int nt = 0; nt < 4; nt++) acc[mt][nt] = (f32x4){0.f, 0.f, 0.f, 0.f};

    float av[16];
    auto loadA = [&](int k0) {
#pragma unroll
        for (int g = 0; g < 4; g++) {
            float4 x = *(const float4*)(Ap + k0 + g * 4);
            av[g * 4 + 0] = x.x; av[g * 4 + 1] = x.y;
            av[g * 4 + 2] = x.z; av[g * 4 + 3] = x.w;
        }
    };
    auto issueB = [&](int k0, int buf) {
        _Float16* d0 = &smem[BHI + buf * BSZ + wave * 1024];
        gll16(BhSrc + k0, d0);
        gll16(BhSrc + (size_t)16 * K + k0, d0 + 512);
        if constexpr (SPLIT == 3) {
            _Float16* d1 = &smem[BLO + buf * BSZ + wave * 1024];
            gll16(BlSrc + k0, d1);
            gll16(BlSrc + (size_t)16 * K + k0, d1 + 512);
        }
    };
    auto storeA = [&]() {
#pragma unroll
        for (int g = 0; g < 2; g++) {
            f16x8 h, l;
#pragma unroll
            for (int j = 0; j < 8; j++) {
                float x = av[g * 8 + j];
                _Float16 hh = (_Float16)x;
                h[j] = hh;
                l[j] = (_Float16)(x - (float)hh);
            }
            *(f16x8*)&smem[AHI + ar * 40 + akc + g * 8] = h;
            if constexpr (SPLIT == 3)
                *(f16x8*)&smem[ALO + ar * 40 + akc + g * 8] = l;
        }
    };

    loadA(0);
    issueB(0, 0);

    int buf = 0;
    for (int k0 = 0; k0 < K; k0 += 32, buf ^= 1) {
        storeA();
        __syncthreads();

        if (k0 + 32 < K) { issueB(k0 + 32, buf ^ 1); loadA(k0 + 32); }

        f16x8 ah[4], al[4], bh[4], bl[4];
#pragma unroll
        for (int mt = 0; mt < 4; mt++) {
            ah[mt] = *(f16x8*)&smem[AHI + (wm + mt * 16 + col) * 40 + quad * 8];
            if constexpr (SPLIT == 3)
                al[mt] = *(f16x8*)&smem[ALO + (wm + mt * 16 + col) * 40 + quad * 8];
        }
#pragma unroll
        for (int nt = 0; nt < 4; nt++) {
            bh[nt] = *(f16x8*)&smem[BHI + buf * BSZ + (wn + nt * 16 + col) * 32 + qe8];
            if constexpr (SPLIT == 3)
                bl[nt] = *(f16x8*)&smem[BLO + buf * BSZ + (wn + nt * 16 + col) * 32 + qe8];
        }
#pragma unroll
        for (int nt = 0; nt < 4; nt++)
#pragma unroll
            for (int mt = 0; mt < 4; mt++) {
                acc[mt][nt] = __builtin_amdgcn_mfma_f32_16x16x32_f16(ah[mt], bh[nt], acc[mt][nt], 0, 0, 0);
                if constexpr (SPLIT == 3) {
                    acc[mt][nt] = __builtin_amdgcn_mfma_f32_16x16x32_f16(ah[mt], bl[nt], acc[mt][nt], 0, 0, 0);
                    acc[mt][nt] = __builtin_amdgcn_mfma_f32_16x16x32_f16(al[mt], bh[nt], acc[mt][nt], 0, 0, 0);
                }
            }
        __syncthreads();
    }

    const float inv = 1.0f / 32.0f;
#pragma unroll
    for (int mt = 0; mt < 4; mt++)
#pragma unroll
        for (int nt = 0; nt < 4; nt++)
#pragma unroll
            for (int r = 0; r < 4; r++) {
                float val = acc[mt][nt][r] * inv;
                size_t idx = (size_t)(m0 + wm + mt * 16 + quad * 4 + r) * N
                           + n0 + wn + nt * 16 + col;
                if constexpr (SPLIT == 3) {
                    _Float16 h = (_Float16)val;
                    if (blockIdx.z == 0) {
                        _Float16 l = (_Float16)(val - (float)h);
                        C[idx] = (unsigned)h2u(h) | ((unsigned)h2u(l) << 16);
                    } else {            // K path: separate hi/lo planes for attn gll
                        Kh[idx] = h;
                        Kl[idx] = (_Float16)(val - (float)h);
                    }
                } else if constexpr (__is_same(CT, _Float16)) {
                    C[idx] = (_Float16)val;
                } else {
                    C[idx] = val;
                }
            }
}

// ---------------------------------------------------------------------------
// MFMA flash attention (causal), XCD-pinned. K staged via global_load_lds from
// hi/lo planes (double-buffered, per-lane 3-bit chunk-XOR source swizzle so
// the unpadded stride-64 b128 frag reads spread across all banks). Softmax
// row-max via DPP (no LDS permutes). l via MFMA row-sum. Softmax on UNSCALED
// scores (reference quirk), /sqrt(64)=8 at the end.
// ---------------------------------------------------------------------------
#define AKH 0
#define AKL 8192
#define AVT 16384
#define AVT_SIZE (64 * 72 + 64)
#define AP  (AVT + AVT_SIZE)
#define AP_WAVE (16 * 72)
#define ATOT (AP + 4 * AP_WAVE)          // 25664 halves = 51.3 KB

__global__ __launch_bounds__(256) void attn_mfma(unsigned* __restrict__ qa,
                                                 const _Float16* __restrict__ khi,
                                                 const _Float16* __restrict__ klo,
                                                 const _Float16* __restrict__ vh)
{
    __shared__ __align__(16) _Float16 smem[ATOT];

    const int i  = blockIdx.x;
    const int j  = i >> 3;
    const int bh = (i & 7) + ((j & 3) << 3);   // pin (b,h) to XCD i&7
    const int qt = (SEQ / 64 - 1) - (j >> 2);
    const int b  = bh >> 4;
    const int h  = bh & 15;
    const int qb = qt * 64;

    const int t    = threadIdx.x;
    const int wave = t >> 6;
    const int lane = t & 63;
    const int quad = lane >> 4;
    const int col  = lane & 15;

    const size_t bbase = (size_t)b * SEQ * DMODEL + (size_t)h * DHEAD;
    const _Float16* vb_ptr = vh + bbase;

    // --- Q fragments (A-operand, hi/lo) from packed uint32 (once) ---
    const int qm = qb + wave * 16 + col;
    f16x8 qhi[2], qlo[2];
    {
        const unsigned* qp = qa + bbase + (size_t)qm * DMODEL + quad * 8;
#pragma unroll
        for (int kt = 0; kt < 2; kt++) {
            uint4 u0 = *(const uint4*)(qp + kt * 32);
            uint4 u1 = *(const uint4*)(qp + kt * 32 + 4);
            unsigned us[8] = {u0.x, u0.y, u0.z, u0.w, u1.x, u1.y, u1.z, u1.w};
#pragma unroll
            for (int jj = 0; jj < 8; jj++) {
                qhi[kt][jj] = u2h((unsigned short)(us[jj] & 0xffffu));
                qlo[kt][jj] = u2h((unsigned short)(us[jj] >> 16));
            }
        }
    }

    // --- K gll staging constants: 8 lanes/row, chunk slot c = lane&7 holds
    //     global chunk c ^ (rowLocal&7); rowLocal = wave*16 + i*8 + (lane>>3).
    const int rl0  = wave * 16 + (lane >> 3);
    const int kswz = (lane & 7) ^ ((lane >> 3) & 7);
    const size_t kbase = ((size_t)b * SEQ + rl0) * DMODEL + h * DHEAD + (kswz << 3);

    auto issueK = [&](int kb, int buf) {
        const _Float16* sh = khi + kbase + (size_t)kb * DMODEL;
        const _Float16* sl = klo + kbase + (size_t)kb * DMODEL;
        _Float16* dh = &smem[AKH + buf * 4096 + wave * 1024];
        _Float16* dl = &smem[AKL + buf * 4096 + wave * 1024];
        gll16(sh, dh);
        gll16(sh + (size_t)8 * DMODEL, dh + 512);
        gll16(sl, dl);
        gll16(sl + (size_t)8 * DMODEL, dl + 512);
    };

    // --- V staging (register prefetch + b16 transpose, as before) ---
    const int srow = t >> 2;
    const int sdg  = (t & 3) << 4;
    const int vswz = (t & 3) * 16;
    f16x8 pv[2];
    auto loadV = [&](int kb) {
        const _Float16* vp = vb_ptr + (size_t)(kb + srow) * DMODEL + sdg;
        pv[0] = *(const f16x8*)vp;
        pv[1] = *(const f16x8*)(vp + 8);
    };

    f16x8 kOnes;
#pragma unroll
    for (int jj = 0; jj < 8; jj++) kOnes[jj] = (_Float16)1.0f;

    float m_i[4];
    f32x4 l4 = (f32x4){0.f, 0.f, 0.f, 0.f};
    f32x4 o[4];
#pragma unroll
    for (int r = 0; r < 4; r++) m_i[r] = -1e30f;
#pragma unroll
    for (int dt = 0; dt < 4; dt++) o[dt] = (f32x4){0.f, 0.f, 0.f, 0.f};

    const int wq0 = qb + wave * 16;
    _Float16* Pw = &smem[AP + wave * AP_WAVE];
    const int cs = col & 7;                  // frag-read swizzle key

    loadV(0);
    issueK(0, 0);

    int buf = 0;
    for (int kb = 0; kb <= qb; kb += 64, buf ^= 1) {
        __syncthreads();                     // prev compute done (drains gll(kb))

#pragma unroll
        for (int jj = 0; jj < 8; jj++) {
            smem[AVT + (sdg + jj    ) * 72 + vswz + srow] = pv[0][jj];
            smem[AVT + (sdg + 8 + jj) * 72 + vswz + srow] = pv[1][jj];
        }
        __syncthreads();                     // staging visible

        if (kb + 64 <= qb) { issueK(kb + 64, buf ^ 1); loadV(kb + 64); }

        // ---- QK^T: 16q x 64keys, split-f16 (3 MFMAs) ----
        f32x4 acc[4];
#pragma unroll
        for (int ct = 0; ct < 4; ct++) acc[ct] = (f32x4){0.f, 0.f, 0.f, 0.f};
#pragma unroll
        for (int kt = 0; kt < 2; kt++) {
#pragma unroll
            for (int ct = 0; ct < 4; ct++) {
                const int off = (ct * 16 + col) * 64 + ((((kt << 2) | quad) ^ cs) << 3);
                f16x8 bhi = *(f16x8*)&smem[AKH + buf * 4096 + off];
                f16x8 blo = *(f16x8*)&smem[AKL + buf * 4096 + off];
                acc[ct] = __builtin_amdgcn_mfma_f32_16x16x32_f16(qhi[kt], bhi, acc[ct], 0, 0, 0);
                acc[ct] = __builtin_amdgcn_mfma_f32_16x16x32_f16(qhi[kt], blo, acc[ct], 0, 0, 0);
                acc[ct] = __builtin_amdgcn_mfma_f32_16x16x32_f16(qlo[kt], bhi, acc[ct], 0, 0, 0);
            }
        }

        // ---- online softmax (row max via DPP, no LDS permutes) ----
        const bool need_mask = (kb + 63 > wq0);
#pragma unroll
        for (int r = 0; r < 4; r++) {
            const int qrow = wq0 + quad * 4 + r;
            float s0 = acc[0][r], s1 = acc[1][r], s2 = acc[2][r], s3 = acc[3][r];
            if (need_mask) {
                s0 = (kb +  0 + col <= qrow) ? s0 : -1e30f;
                s1 = (kb + 16 + col <= qrow) ? s1 : -1e30f;
                s2 = (kb + 32 + col <= qrow) ? s2 : -1e30f;
                s3 = (kb + 48 + col <= qrow) ? s3 : -1e30f;
            }
            float rm = dpp_max16(fmaxf(fmaxf(s0, s1), fmaxf(s2, s3)));
            const float mnew  = fmaxf(m_i[r], rm);
            const float alpha = __expf(m_i[r] - mnew);
            const float p0 = __expf(s0 - mnew), p1 = __expf(s1 - mnew);
            const float p2 = __expf(s2 - mnew), p3 = __expf(s3 - mnew);
            m_i[r] = mnew;
            l4[r] *= alpha;
#pragma unroll
            for (int dt = 0; dt < 4; dt++) o[dt][r] *= alpha;
            const int prow = quad * 4 + r;
            Pw[prow * 72 + col     ] = (_Float16)p0;
            Pw[prow * 72 + col + 16] = (_Float16)p1;
            Pw[prow * 72 + col + 32] = (_Float16)p2;
            Pw[prow * 72 + col + 48] = (_Float16)p3;
        }

        // ---- PV: O += P @ V; l += P @ ones ----
#pragma unroll
        for (int kt = 0; kt < 2; kt++) {
            f16x8 a = *(f16x8*)&Pw[col * 72 + kt * 32 + quad * 8];
            l4 = __builtin_amdgcn_mfma_f32_16x16x32_f16(a, kOnes, l4, 0, 0, 0);
#pragma unroll
            for (int dt = 0; dt < 4; dt++) {
                f16x8 bv = *(f16x8*)&smem[AVT + (dt * 16 + col) * 72 + (dt & 3) * 16 + kt * 32 + quad * 8];
                o[dt] = __builtin_amdgcn_mfma_f32_16x16x32_f16(a, bv, o[dt], 0, 0, 0);
            }
        }
    }

    // ---- epilogue: /l, /8; write att (fp32 bits) over packed qh ----
#pragma unroll
    for (int r = 0; r < 4; r++) {
        const float inv = 1.0f / (l4[r] * 8.0f);
        const int q = wq0 + quad * 4 + r;
        unsigned* op = qa + bbase + (size_t)q * DMODEL;
#pragma unroll
        for (int dt = 0; dt < 4; dt++)
            op[dt * 16 + col] = __float_as_uint(o[dt][r] * inv);
    }
}

// ---------------------------------------------------------------------------
// Launch. Inputs: q, k, v, mask(ignored), Wq, Wk, Wv, Wo — all fp32.
// ws (32 MB): qh packed u32 [0,16); khi f16 [16,24); klo f16 [24,32).
// d_out (16 MB) rotating scratch: weight planes [0,10 MB); vh f16 [0,8) after
// QK; wohiT -> khi region (dead after attn); out overwrites d_out at the end.
// ---------------------------------------------------------------------------
extern "C" void kernel_launch(void* const* d_in, const int* in_sizes, int n_in,
                              void* d_out, int out_size, void* d_ws, size_t ws_size,
                              hipStream_t stream)
{
    const float* q  = (const float*)d_in[0];
    const float* k  = (const float*)d_in[1];
    const float* v  = (const float*)d_in[2];
    const float* Wq = (const float*)d_in[4];
    const float* Wk = (const float*)d_in[5];
    const float* Wv = (const float*)d_in[6];
    const float* Wo = (const float*)d_in[7];
    float* out = (float*)d_out;

    const int    M   = BATCH * SEQ;             // 4096
    const size_t npe = (size_t)M * DMODEL;      // 4,194,304
    const size_t PW  = (size_t)DMODEL * DMODEL; // 1M halves per plane

    unsigned* qh    = (unsigned*)d_ws;                  // ws[0,16 MB)
    _Float16* khi_p = (_Float16*)(qh + npe);            // ws[16,24 MB)
    _Float16* klo_p = khi_p + npe;                      // ws[24,32 MB)

    _Float16* dh    = (_Float16*)d_out;
    _Float16* qhiT  = dh;
    _Float16* qloT  = dh + PW;
    _Float16* khiT  = dh + 2 * PW;
    _Float16* kloT  = dh + 3 * PW;
    _Float16* vhiT  = dh + 4 * PW;
    _Float16* vh    = dh;                               // d_out[0,8 MB) after QK
    _Float16* wohiT = khi_p;                            // khi region after attn

    dim3 b256(256);
    dim3 pk(DMODEL / 64, DMODEL / 64, 3);
    dim3 pk1(DMODEL / 64, DMODEL / 64, 1);
    dim3 gqk(M / 128, DMODEL / 128, 2);
    dim3 g1(M / 128, DMODEL / 128, 1);
    dim3 agrid(1024);

    pack_qkv<<<pk, b256, 0, stream>>>(Wq, Wk, Wv, qhiT, qloT, khiT, kloT, vhiT);
    gemm_mfma<3, unsigned><<<gqk, b256, 0, stream>>>(q, k, qhiT, qloT, khiT, kloT,
                                                     qh, nullptr, khi_p, klo_p,
                                                     DMODEL, DMODEL);
    gemm_mfma<1, _Float16><<<g1, b256, 0, stream>>>(v, v, vhiT, nullptr, vhiT, nullptr,
                                                    vh, vh, nullptr, nullptr,
                                                    DMODEL, DMODEL);
    attn_mfma<<<agrid, b256, 0, stream>>>(qh, khi_p, klo_p, vh);
    pack_one<<<pk1, b256, 0, stream>>>(Wo, wohiT);
    gemm_mfma<1, float><<<g1, b256, 0, stream>>>((const float*)qh, (const float*)qh,
                                                 wohiT, nullptr, wohiT, nullptr,
                                                 out, out, nullptr, nullptr,
                                                 DMODEL, DMODEL);
}